// Round 1
// baseline (1995.748 us; speedup 1.0000x reference)
//
#include <hip/hip_runtime.h>
#include <math.h>

// Problem constants
#define BB 2
#define SS 400
#define II 80
#define HH 128
#define FF 256          // 2*H
#define NN 401          // S+1
#define G4 512          // 4*H
#define MAXSEG 50
#define NCLS 50
#define KH 100          // rows of W1 / Wc1 / Wb1

// d_out layout (floats): scores | cls | bin | pred | prev
#define SCORES_OFF 0
#define CLS_OFF    (BB*NN*NN)                 // 321602
#define BIN_OFF    (CLS_OFF + BB*SS*NCLS)     // 361602
#define PRED_OFF   (BIN_OFF + BB*SS*2)        // 363202
#define PREV_OFF   (PRED_OFF + BB)            // 363204

// workspace layout (floats)
#define WS_GX      0                          // 4 * S * 512 = 819200
#define WS_RNN     (WS_GX + 4*SS*G4)          // B*S*F = 204800
#define WS_CUM     (WS_RNN + BB*SS*FF)        // B*N*F = 205312
#define WS_PXD     (WS_CUM + BB*NN*FF)        // B*N*100
#define WS_PXE     (WS_PXD + BB*NN*KH)
#define WS_PART    (WS_PXE + BB*NN*KH)        // B*16*F
// total ~1.4M floats ~5.6MB

__device__ __forceinline__ float prelu_f(float x, float a) {
    return x >= 0.f ? x : a * x;
}

// ---------------- K1: gx[db][t][g] = b[g] + x[b, xt, :] . Wi[g, :] ---------
__global__ void k_lstm_pre(const float* __restrict__ x,
                           const float* __restrict__ Wi_f, const float* __restrict__ b_f,
                           const float* __restrict__ Wi_b, const float* __restrict__ b_b,
                           float* __restrict__ gx) {
    int blk = blockIdx.x;          // db*S + t
    int t = blk % SS;
    int db = blk / SS;             // dir*2 + b
    int b = db & 1, dir = db >> 1;
    const float* Wi = dir ? Wi_b : Wi_f;
    const float* bias = dir ? b_b : b_f;
    int xt = dir ? (SS - 1 - t) : t;

    __shared__ __align__(16) float xr[II];
    int tid = threadIdx.x;
    if (tid < II) xr[tid] = x[(b * SS + xt) * II + tid];
    __syncthreads();

    for (int g = tid; g < G4; g += 256) {
        const float* w = Wi + g * II;
        float acc = bias[g];
#pragma unroll
        for (int i = 0; i < II; i += 4) {
            float4 w4 = *(const float4*)(w + i);
            acc += w4.x * xr[i] + w4.y * xr[i + 1] + w4.z * xr[i + 2] + w4.w * xr[i + 3];
        }
        gx[(db * SS + t) * G4 + g] = acc;
    }
}

// ---------------- K2: recurrent LSTM, 4 blocks (dir,b), 512 threads --------
__global__ __launch_bounds__(512, 2)
void k_lstm_rec(const float* __restrict__ Wh_f, const float* __restrict__ Wh_b,
                const float* __restrict__ gx, float* __restrict__ rnn_out) {
    int db = blockIdx.x;
    int b = db & 1, dir = db >> 1;
    const float* Wh = dir ? Wh_b : Wh_f;
    int t = threadIdx.x;

    float w[HH];
#pragma unroll
    for (int j = 0; j < HH; j += 4) {
        float4 v = *(const float4*)(Wh + t * HH + j);
        w[j] = v.x; w[j + 1] = v.y; w[j + 2] = v.z; w[j + 3] = v.w;
    }

    __shared__ __align__(16) float hs[HH];
    __shared__ float gsh[G4];
    if (t < HH) hs[t] = 0.f;
    float c = 0.f;
    __syncthreads();

    const float* gxp = gx + db * SS * G4;
    float gcur = gxp[t];                    // prefetch step 0
    for (int step = 0; step < SS; ++step) {
        float gnext = (step + 1 < SS) ? gxp[(step + 1) * G4 + t] : 0.f;
        float acc = gcur;
#pragma unroll
        for (int j = 0; j < HH; j += 4) {
            float4 h4 = *(const float4*)(hs + j);
            acc += w[j] * h4.x + w[j + 1] * h4.y + w[j + 2] * h4.z + w[j + 3] * h4.w;
        }
        gsh[t] = acc;
        __syncthreads();
        if (t < HH) {
            float gi = gsh[t], gf = gsh[HH + t], gg = gsh[2 * HH + t], go = gsh[3 * HH + t];
            float si = 1.f / (1.f + __expf(-gi));
            float sf = 1.f / (1.f + __expf(-gf));
            float so = 1.f / (1.f + __expf(-go));
            c = sf * c + si * tanhf(gg);
            float h = so * tanhf(c);
            hs[t] = h;
            int xt = dir ? (SS - 1 - step) : step;
            rnn_out[(b * SS + xt) * FF + dir * HH + t] = h;
        }
        __syncthreads();
        gcur = gnext;
    }
}

// ---------------- K3: cumsum over time (3 passes) --------------------------
#define CHUNK 25
#define NCH 16
__global__ void k_cum_part(const float* __restrict__ rnn, float* __restrict__ part) {
    int blk = blockIdx.x;           // b*NCH + c
    int c = blk % NCH, b = blk / NCH;
    int f = threadIdx.x;
    float s = 0.f;
    for (int r = 0; r < CHUNK; ++r) s += rnn[(b * SS + c * CHUNK + r) * FF + f];
    part[blk * FF + f] = s;
}
__global__ void k_cum_off(float* __restrict__ part) {
    int b = blockIdx.x;
    int f = threadIdx.x;
    float run = 0.f;
    for (int c = 0; c < NCH; ++c) {
        int idx = (b * NCH + c) * FF + f;
        float tmp = part[idx];
        part[idx] = run;
        run += tmp;
    }
}
__global__ void k_cum_write(const float* __restrict__ rnn, const float* __restrict__ part,
                            float* __restrict__ cum) {
    int blk = blockIdx.x;           // b*NCH + c
    int c = blk % NCH, b = blk / NCH;
    int f = threadIdx.x;
    float run = part[blk * FF + f];
    cum[(b * NN + c * CHUNK) * FF + f] = run;
    for (int idx = 1; idx <= CHUNK; ++idx) {
        run += rnn[(b * SS + c * CHUNK + idx - 1) * FF + f];
        cum[(b * NN + c * CHUNK + idx) * FF + f] = run;
    }
}

// ---------------- K4: pxd/pxe = prelu(xp,a1) @ W1d.T / W1e.T ---------------
__global__ void k_pxde(const float* __restrict__ rnn, const float* __restrict__ W1,
                       const float* __restrict__ a1p,
                       float* __restrict__ pxd, float* __restrict__ pxe) {
    int blk = blockIdx.x;           // b*N + n
    int n = blk % NN, b = blk / NN;
    int tid = threadIdx.x;
    float a1 = a1p[0];
    __shared__ __align__(16) float px[FF];
    float rv = (n == 0) ? 0.f : rnn[(b * SS + n - 1) * FF + tid];
    px[tid] = prelu_f(rv, a1);
    __syncthreads();

    if (tid < KH) {
        const float* w = W1 + tid * (3 * FF) + FF;    // W1d row
        float acc = 0.f;
#pragma unroll 8
        for (int f = 0; f < FF; f += 4) {
            float4 w4 = *(const float4*)(w + f);
            acc += w4.x * px[f] + w4.y * px[f + 1] + w4.z * px[f + 2] + w4.w * px[f + 3];
        }
        pxd[blk * KH + tid] = acc;
    } else if (tid >= 128 && tid < 128 + KH) {
        int k = tid - 128;
        const float* w = W1 + k * (3 * FF) + 2 * FF;  // W1e row
        float acc = 0.f;
#pragma unroll 8
        for (int f = 0; f < FF; f += 4) {
            float4 w4 = *(const float4*)(w + f);
            acc += w4.x * px[f] + w4.y * px[f + 1] + w4.z * px[f + 2] + w4.w * px[f + 3];
        }
        pxe[blk * KH + k] = acc;
    }
}

// ---------------- K5: scores --------------------------------------------
// block = (b, i, jt); 32 j's per block; 256 threads.
// lane&31 = j_local; (wave*2 + lane>>5) = k-group (13 k's each, 8 groups = 104 >= 100)
#define JT 32
#define JTILES 13
#define DPAD 260
__global__ __launch_bounds__(256, 4)
void k_scores(const float* __restrict__ cum, const float* __restrict__ W1,
              const float* __restrict__ pxd, const float* __restrict__ pxe,
              const float* __restrict__ b1, const float* __restrict__ W2,
              const float* __restrict__ b2p,
              const float* __restrict__ a1p, const float* __restrict__ a2p,
              float* __restrict__ scores) {
    int blk = blockIdx.x;
    int jt = blk % JTILES;
    int i = (blk / JTILES) % NN;
    int b = blk / (JTILES * NN);
    int tid = threadIdx.x;
    float a1 = a1p[0], a2 = a2p[0];

    __shared__ __align__(16) float ci[FF];
    __shared__ __align__(16) float dt[JT][DPAD];
    __shared__ float red[4][JT];

    ci[tid] = cum[(b * NN + i) * FF + tid];
    __syncthreads();

    int jbase = jt * JT;
#pragma unroll 4
    for (int r = 0; r < JT; ++r) {
        int jg = jbase + r;
        float v = 0.f;
        if (jg <= NN - 1) v = cum[(b * NN + jg) * FF + tid] - ci[tid];
        dt[r][tid] = prelu_f(v, a1);
    }
    __syncthreads();

    int lane = tid & 63;
    int wv = tid >> 6;
    int jl = lane & 31;
    int hh = lane >> 5;
    int kg = wv * 2 + hh;               // 0..7

    const float* wp[13];
#pragma unroll
    for (int kk = 0; kk < 13; ++kk) {
        int k = kg * 13 + kk;
        int sk = (k < KH) ? k : 0;
        wp[kk] = W1 + sk * (3 * FF);    // W1c row
    }

    float acc[13];
#pragma unroll
    for (int kk = 0; kk < 13; ++kk) acc[kk] = 0.f;

    for (int f4 = 0; f4 < FF / 4; ++f4) {
        float4 d4 = *(const float4*)(&dt[jl][f4 * 4]);
#pragma unroll
        for (int kk = 0; kk < 13; ++kk) {
            float4 w4 = *(const float4*)(wp[kk] + f4 * 4);
            acc[kk] += w4.x * d4.x + w4.y * d4.y + w4.z * d4.z + w4.w * d4.w;
        }
    }

    int jg = jbase + jl;
    int jgs = (jg <= NN - 1) ? jg : NN - 1;
    float s = 0.f;
#pragma unroll
    for (int kk = 0; kk < 13; ++kk) {
        int k = kg * 13 + kk;
        if (k < KH) {
            float hv = acc[kk] + pxd[(b * NN + i) * KH + k] + pxe[(b * NN + jgs) * KH + k] + b1[k];
            s += W2[k] * prelu_f(hv, a2);
        }
    }
    s += __shfl_xor(s, 32);
    if (hh == 0) red[wv][jl] = s;
    __syncthreads();
    if (tid < JT) {
        int jg2 = jbase + tid;
        if (jg2 <= NN - 1) {
            float tot = red[0][tid] + red[1][tid] + red[2][tid] + red[3][tid] + b2p[0];
            scores[(b * NN + i) * NN + jg2] = tot;
        }
    }
}

// ---------------- K6: cls / bin heads -------------------------------------
__global__ void k_heads(const float* __restrict__ rnn,
                        const float* __restrict__ ac1p, const float* __restrict__ Wc1,
                        const float* __restrict__ bc1, const float* __restrict__ ac2p,
                        const float* __restrict__ Wc2, const float* __restrict__ bc2,
                        const float* __restrict__ ab1p, const float* __restrict__ Wb1,
                        const float* __restrict__ bb1, const float* __restrict__ ab2p,
                        const float* __restrict__ Wb2, const float* __restrict__ bb2,
                        float* __restrict__ cls_out, float* __restrict__ bin_out) {
    int blk = blockIdx.x;           // b*S + t
    int ts = blk % SS, b = blk / SS;
    int tid = threadIdx.x;
    __shared__ __align__(16) float prc[FF], prb[FF];
    __shared__ __align__(16) float uc[KH], ub[KH];
    float ac1 = ac1p[0], ab1 = ab1p[0];
    for (int f = tid; f < FF; f += 128) {
        float rv = rnn[(b * SS + ts) * FF + f];
        prc[f] = prelu_f(rv, ac1);
        prb[f] = prelu_f(rv, ab1);
    }
    __syncthreads();
    if (tid < KH) {
        const float* wc = Wc1 + tid * FF;
        const float* wb = Wb1 + tid * FF;
        float ac = 0.f, ab = 0.f;
#pragma unroll 8
        for (int f = 0; f < FF; f += 4) {
            float4 c4 = *(const float4*)(wc + f);
            float4 b4 = *(const float4*)(wb + f);
            ac += c4.x * prc[f] + c4.y * prc[f + 1] + c4.z * prc[f + 2] + c4.w * prc[f + 3];
            ab += b4.x * prb[f] + b4.y * prb[f + 1] + b4.z * prb[f + 2] + b4.w * prb[f + 3];
        }
        uc[tid] = prelu_f(ac + bc1[tid], ac2p[0]);
        ub[tid] = prelu_f(ab + bb1[tid], ab2p[0]);
    }
    __syncthreads();
    if (tid < NCLS) {
        const float* w = Wc2 + tid * KH;
        float acc = bc2[tid];
#pragma unroll
        for (int q = 0; q < KH; q += 4) {
            float4 w4 = *(const float4*)(w + q);
            acc += w4.x * uc[q] + w4.y * uc[q + 1] + w4.z * uc[q + 2] + w4.w * uc[q + 3];
        }
        cls_out[(b * SS + ts) * NCLS + tid] = acc;
    }
    if (tid >= 64 && tid < 66) {
        int o = tid - 64;
        const float* w = Wb2 + o * KH;
        float acc = bb2[o];
#pragma unroll
        for (int q = 0; q < KH; q += 4) {
            float4 w4 = *(const float4*)(w + q);
            acc += w4.x * ub[q] + w4.y * ub[q + 1] + w4.z * ub[q + 2] + w4.w * ub[q + 3];
        }
        bin_out[(b * SS + ts) * 2 + o] = acc;
    }
}

// ---------------- K7: DP segment search -----------------------------------
__global__ void k_dp(const float* __restrict__ scores, const int* __restrict__ lengths,
                     float* __restrict__ predF, float* __restrict__ prevF) {
    int b = blockIdx.x;
    int lane = threadIdx.x;          // 64 threads, 1 wave
    __shared__ float bl[NN];
    for (int idx = lane; idx < NN; idx += 64) bl[idx] = 0.f;
    __syncthreads();
    if (lane == 0) prevF[b * NN] = 0.f;

    // prefetch column i=1
    int lo = 0, cnt = 1;
    float sc = (lane < cnt) ? scores[(b * NN + lo + lane) * NN + 1] : 0.f;

    for (int i = 1; i <= NN - 1; ++i) {
        int myk = lo + lane;
        float cand = (lane < cnt) ? bl[myk] + sc : -INFINITY;
        int idx = myk;
        // prefetch next column
        int lo2 = (i + 1 > MAXSEG) ? (i + 1 - MAXSEG) : 0;
        int cnt2 = i + 1 - lo2;
        float scn = 0.f;
        if (i + 1 <= NN - 1 && lane < cnt2)
            scn = scores[(b * NN + lo2 + lane) * NN + (i + 1)];
        // argmax reduce (max value, tie -> min index, matches numpy argmax)
#pragma unroll
        for (int off = 32; off; off >>= 1) {
            float vo = __shfl_down(cand, off);
            int io = __shfl_down(idx, off);
            if (vo > cand || (vo == cand && io < idx)) { cand = vo; idx = io; }
        }
        if (lane == 0) {
            bl[i] = cand;
            prevF[b * NN + i] = (float)idx;
        }
        __syncthreads();
        sc = scn;
        lo = lo2; cnt = cnt2;
    }
    if (lane == 0) {
        int len = lengths[b];
        predF[b] = bl[len];
    }
}

// ---------------- launch ---------------------------------------------------
extern "C" void kernel_launch(void* const* d_in, const int* in_sizes, int n_in,
                              void* d_out, int out_size, void* d_ws, size_t ws_size,
                              hipStream_t stream) {
    const float* x    = (const float*)d_in[0];
    const int* lengths= (const int*)d_in[1];
    const float* Wi_f = (const float*)d_in[2];
    const float* Wh_f = (const float*)d_in[3];
    const float* b_f  = (const float*)d_in[4];
    const float* Wi_b = (const float*)d_in[5];
    const float* Wh_b = (const float*)d_in[6];
    const float* b_b  = (const float*)d_in[7];
    const float* a1   = (const float*)d_in[8];
    const float* W1   = (const float*)d_in[9];
    const float* b1   = (const float*)d_in[10];
    const float* a2   = (const float*)d_in[11];
    const float* W2   = (const float*)d_in[12];
    const float* b2   = (const float*)d_in[13];
    const float* ac1  = (const float*)d_in[14];
    const float* Wc1  = (const float*)d_in[15];
    const float* bc1  = (const float*)d_in[16];
    const float* ac2  = (const float*)d_in[17];
    const float* Wc2  = (const float*)d_in[18];
    const float* bc2  = (const float*)d_in[19];
    const float* ab1  = (const float*)d_in[20];
    const float* Wb1  = (const float*)d_in[21];
    const float* bb1  = (const float*)d_in[22];
    const float* ab2  = (const float*)d_in[23];
    const float* Wb2  = (const float*)d_in[24];
    const float* bb2  = (const float*)d_in[25];

    float* out = (float*)d_out;
    float* scores = out + SCORES_OFF;
    float* cls    = out + CLS_OFF;
    float* bin    = out + BIN_OFF;
    float* pred   = out + PRED_OFF;
    float* prev   = out + PREV_OFF;

    float* ws   = (float*)d_ws;
    float* gx   = ws + WS_GX;
    float* rnn  = ws + WS_RNN;
    float* cum  = ws + WS_CUM;
    float* pxd  = ws + WS_PXD;
    float* pxe  = ws + WS_PXE;
    float* part = ws + WS_PART;

    k_lstm_pre<<<4 * SS, 256, 0, stream>>>(x, Wi_f, b_f, Wi_b, b_b, gx);
    k_lstm_rec<<<4, 512, 0, stream>>>(Wh_f, Wh_b, gx, rnn);
    k_cum_part<<<BB * NCH, FF, 0, stream>>>(rnn, part);
    k_cum_off<<<BB, FF, 0, stream>>>(part);
    k_cum_write<<<BB * NCH, FF, 0, stream>>>(rnn, part, cum);
    k_pxde<<<BB * NN, 256, 0, stream>>>(rnn, W1, a1, pxd, pxe);
    k_scores<<<BB * NN * JTILES, 256, 0, stream>>>(cum, W1, pxd, pxe, b1, W2, b2, a1, a2, scores);
    k_heads<<<BB * SS, 128, 0, stream>>>(rnn, ac1, Wc1, bc1, ac2, Wc2, bc2,
                                         ab1, Wb1, bb1, ab2, Wb2, bb2, cls, bin);
    k_dp<<<BB, 64, 0, stream>>>(scores, lengths, pred, prev);
}

// Round 2
// 1166.953 us; speedup vs baseline: 1.7102x; 1.7102x over previous
//
#include <hip/hip_runtime.h>
#include <math.h>

// Problem constants
#define BB 2
#define SS 400
#define II 80
#define HH 128
#define FF 256          // 2*H
#define NN 401          // S+1
#define G4 512          // 4*H
#define MAXSEG 50
#define NCLS 50
#define KH 100          // rows of W1 / Wc1 / Wb1
#define KP 112          // KH padded to 7*16 for MFMA

// d_out layout (floats): scores | cls | bin | pred | prev
#define SCORES_OFF 0
#define CLS_OFF    (BB*NN*NN)
#define BIN_OFF    (CLS_OFF + BB*SS*NCLS)
#define PRED_OFF   (BIN_OFF + BB*SS*2)
#define PREV_OFF   (PRED_OFF + BB)

// workspace layout (float slots)
#define WS_GX      0                          // 4*S*512 = 819200
#define WS_RNN     (WS_GX + 4*SS*G4)          // B*S*F
#define WS_CUM     (WS_RNN + BB*SS*FF)        // B*N*F
#define WS_PXD     (WS_CUM + BB*NN*FF)        // B*N*KP
#define WS_PXE     (WS_PXD + BB*NN*KP)
#define WS_PART    (WS_PXE + BB*NN*KP)        // B*16*F
#define WS_WH      (WS_PART + BB*16*FF)       // W1c hi bf16: KP*FF shorts = KP*FF/2 floats
#define WS_WL      (WS_WH + (KP*FF)/2)
#define WS_W2P     (WS_WL + (KP*FF)/2)        // KP floats
#define WS_B1P     (WS_W2P + KP)              // KP floats

typedef __attribute__((ext_vector_type(8))) short short8;
typedef __attribute__((ext_vector_type(4))) float f32x4;

__device__ __forceinline__ float prelu_f(float x, float a) {
    return x >= 0.f ? x : a * x;
}
__device__ __forceinline__ unsigned short f2bf(float x) {
    union { float f; unsigned u; } v; v.f = x;
    unsigned r = v.u + 0x7fffu + ((v.u >> 16) & 1u);   // RNE
    return (unsigned short)(r >> 16);
}
__device__ __forceinline__ float bf2f(unsigned short h) {
    union { unsigned u; float f; } v; v.u = ((unsigned)h) << 16; return v.f;
}

// ---------------- K0: prep W1c bf16 hi/lo + padded W2/b1 -------------------
__global__ void k_prep(const float* __restrict__ W1, const float* __restrict__ W2,
                       const float* __restrict__ b1,
                       short* __restrict__ wh, short* __restrict__ wl,
                       float* __restrict__ w2p, float* __restrict__ b1p) {
    int k = blockIdx.x;        // 0..111
    int f = threadIdx.x;       // 0..255
    float w = (k < KH) ? W1[k * (3 * FF) + f] : 0.f;
    unsigned short hi = f2bf(w);
    unsigned short lo = f2bf(w - bf2f(hi));
    wh[k * FF + f] = (short)hi;
    wl[k * FF + f] = (short)lo;
    if (f == 0) {
        w2p[k] = (k < KH) ? W2[k] : 0.f;
        b1p[k] = (k < KH) ? b1[k] : 0.f;
    }
}

// ---------------- K1: gx[db][t][g] = b[g] + x[b, xt, :] . Wi[g, :] ---------
__global__ void k_lstm_pre(const float* __restrict__ x,
                           const float* __restrict__ Wi_f, const float* __restrict__ b_f,
                           const float* __restrict__ Wi_b, const float* __restrict__ b_b,
                           float* __restrict__ gx) {
    int blk = blockIdx.x;          // db*S + t
    int t = blk % SS;
    int db = blk / SS;             // dir*2 + b
    int b = db & 1, dir = db >> 1;
    const float* Wi = dir ? Wi_b : Wi_f;
    const float* bias = dir ? b_b : b_f;
    int xt = dir ? (SS - 1 - t) : t;

    __shared__ __align__(16) float xr[II];
    int tid = threadIdx.x;
    if (tid < II) xr[tid] = x[(b * SS + xt) * II + tid];
    __syncthreads();

    for (int g = tid; g < G4; g += 256) {
        const float* w = Wi + g * II;
        float acc = bias[g];
#pragma unroll
        for (int i = 0; i < II; i += 4) {
            float4 w4 = *(const float4*)(w + i);
            acc += w4.x * xr[i] + w4.y * xr[i + 1] + w4.z * xr[i + 2] + w4.w * xr[i + 3];
        }
        gx[(db * SS + t) * G4 + g] = acc;
    }
}

// ---------------- K2: recurrent LSTM, 4 blocks (dir,b), 512 threads --------
__global__ __launch_bounds__(512, 2)
void k_lstm_rec(const float* __restrict__ Wh_f, const float* __restrict__ Wh_b,
                const float* __restrict__ gx, float* __restrict__ rnn_out) {
    int db = blockIdx.x;
    int b = db & 1, dir = db >> 1;
    const float* Wh = dir ? Wh_b : Wh_f;
    int t = threadIdx.x;

    float w[HH];
#pragma unroll
    for (int j = 0; j < HH; j += 4) {
        float4 v = *(const float4*)(Wh + t * HH + j);
        w[j] = v.x; w[j + 1] = v.y; w[j + 2] = v.z; w[j + 3] = v.w;
    }

    __shared__ __align__(16) float hs[HH];
    __shared__ float gsh[G4];
    if (t < HH) hs[t] = 0.f;
    float c = 0.f;
    __syncthreads();

    const float* gxp = gx + db * SS * G4;
    float gcur = gxp[t];                    // prefetch step 0
    for (int step = 0; step < SS; ++step) {
        float gnext = (step + 1 < SS) ? gxp[(step + 1) * G4 + t] : 0.f;
        float acc = gcur;
#pragma unroll
        for (int j = 0; j < HH; j += 4) {
            float4 h4 = *(const float4*)(hs + j);
            acc += w[j] * h4.x + w[j + 1] * h4.y + w[j + 2] * h4.z + w[j + 3] * h4.w;
        }
        gsh[t] = acc;
        __syncthreads();
        if (t < HH) {
            float gi = gsh[t], gf = gsh[HH + t], gg = gsh[2 * HH + t], go = gsh[3 * HH + t];
            float si = 1.f / (1.f + __expf(-gi));
            float sf = 1.f / (1.f + __expf(-gf));
            float so = 1.f / (1.f + __expf(-go));
            c = sf * c + si * tanhf(gg);
            float h = so * tanhf(c);
            hs[t] = h;
            int xt = dir ? (SS - 1 - step) : step;
            rnn_out[(b * SS + xt) * FF + dir * HH + t] = h;
        }
        __syncthreads();
        gcur = gnext;
    }
}

// ---------------- K3: cumsum over time (3 passes) --------------------------
#define CHUNK 25
#define NCH 16
__global__ void k_cum_part(const float* __restrict__ rnn, float* __restrict__ part) {
    int blk = blockIdx.x;           // b*NCH + c
    int c = blk % NCH, b = blk / NCH;
    int f = threadIdx.x;
    float s = 0.f;
    for (int r = 0; r < CHUNK; ++r) s += rnn[(b * SS + c * CHUNK + r) * FF + f];
    part[blk * FF + f] = s;
}
__global__ void k_cum_off(float* __restrict__ part) {
    int b = blockIdx.x;
    int f = threadIdx.x;
    float run = 0.f;
    for (int c = 0; c < NCH; ++c) {
        int idx = (b * NCH + c) * FF + f;
        float tmp = part[idx];
        part[idx] = run;
        run += tmp;
    }
}
__global__ void k_cum_write(const float* __restrict__ rnn, const float* __restrict__ part,
                            float* __restrict__ cum) {
    int blk = blockIdx.x;           // b*NCH + c
    int c = blk % NCH, b = blk / NCH;
    int f = threadIdx.x;
    float run = part[blk * FF + f];
    cum[(b * NN + c * CHUNK) * FF + f] = run;
    for (int idx = 1; idx <= CHUNK; ++idx) {
        run += rnn[(b * SS + c * CHUNK + idx - 1) * FF + f];
        cum[(b * NN + c * CHUNK + idx) * FF + f] = run;
    }
}

// ---------------- K4: pxd/pxe = prelu(xp,a1) @ W1d.T / W1e.T (stride KP) ---
__global__ void k_pxde(const float* __restrict__ rnn, const float* __restrict__ W1,
                       const float* __restrict__ a1p,
                       float* __restrict__ pxd, float* __restrict__ pxe) {
    int blk = blockIdx.x;           // b*N + n
    int n = blk % NN, b = blk / NN;
    int tid = threadIdx.x;
    float a1 = a1p[0];
    __shared__ __align__(16) float px[FF];
    float rv = (n == 0) ? 0.f : rnn[(b * SS + n - 1) * FF + tid];
    px[tid] = prelu_f(rv, a1);
    __syncthreads();

    if (tid < KH) {
        const float* w = W1 + tid * (3 * FF) + FF;    // W1d row
        float acc = 0.f;
#pragma unroll 8
        for (int f = 0; f < FF; f += 4) {
            float4 w4 = *(const float4*)(w + f);
            acc += w4.x * px[f] + w4.y * px[f + 1] + w4.z * px[f + 2] + w4.w * px[f + 3];
        }
        pxd[blk * KP + tid] = acc;
    } else if (tid >= KH && tid < KP) {
        pxd[blk * KP + tid] = 0.f;                    // pad
    } else if (tid >= 128 && tid < 128 + KH) {
        int k = tid - 128;
        const float* w = W1 + k * (3 * FF) + 2 * FF;  // W1e row
        float acc = 0.f;
#pragma unroll 8
        for (int f = 0; f < FF; f += 4) {
            float4 w4 = *(const float4*)(w + f);
            acc += w4.x * px[f] + w4.y * px[f + 1] + w4.z * px[f + 2] + w4.w * px[f + 3];
        }
        pxe[blk * KP + k] = acc;
    } else if (tid >= 128 + KH && tid < 128 + KP) {
        pxe[blk * KP + (tid - 128)] = 0.f;            // pad
    }
}

// ---------------- K5: scores via MFMA (bf16 hi/lo split A, bf16 W) ---------
// block = (b, i, jt): 32 j's; 4 waves; wave wv covers k-tiles {2wv, 2wv+1} (7 skipped)
#define JT 32
#define JTILES 13
#define AP 264          // row stride in shorts (256 + 8 pad)
__global__ __launch_bounds__(256, 2)
void k_scores(const float* __restrict__ cum,
              const short* __restrict__ wh, const short* __restrict__ wl,
              const float* __restrict__ pxd, const float* __restrict__ pxe,
              const float* __restrict__ b1p, const float* __restrict__ w2p,
              const float* __restrict__ b2p,
              const float* __restrict__ a1p, const float* __restrict__ a2p,
              float* __restrict__ scores) {
    int blk = blockIdx.x;
    int jt = blk % JTILES;
    int i = (blk / JTILES) % NN;
    int b = blk / (JTILES * NN);
    int tid = threadIdx.x;
    float a1 = a1p[0], a2 = a2p[0];
    int jbase = jt * JT;

    __shared__ __align__(16) float ci[FF];
    __shared__ __align__(16) short dth[JT][AP];
    __shared__ __align__(16) short dtl[JT][AP];
    __shared__ float red[4][JT];

    ci[tid] = cum[(b * NN + i) * FF + tid];
    __syncthreads();

    // ---- build A tile: row = tid>>3, f-chunk = (tid&7)*32
    {
        int row = tid >> 3;
        int fb = (tid & 7) * 32;
        int jg = jbase + row;
        int jc = (jg <= SS) ? jg : SS;
        const float* cj = cum + (b * NN + jc) * FF + fb;
#pragma unroll
        for (int c8 = 0; c8 < 4; ++c8) {          // 8 elements per chunk
            float4 v0 = *(const float4*)(cj + c8 * 8);
            float4 v1 = *(const float4*)(cj + c8 * 8 + 4);
            union { short8 s; unsigned short u[8]; } h8, l8;
            float dv[8] = { v0.x, v0.y, v0.z, v0.w, v1.x, v1.y, v1.z, v1.w };
#pragma unroll
            for (int e = 0; e < 8; ++e) {
                float d = prelu_f(dv[e] - ci[fb + c8 * 8 + e], a1);
                unsigned short hi = f2bf(d);
                h8.u[e] = hi;
                l8.u[e] = f2bf(d - bf2f(hi));
            }
            *(short8*)(&dth[row][fb + c8 * 8]) = h8.s;
            *(short8*)(&dtl[row][fb + c8 * 8]) = l8.s;
        }
    }
    __syncthreads();

    int lane = tid & 63;
    int wv = tid >> 6;
    int quad = lane >> 4;
    int l15 = lane & 15;
    int kt0 = wv * 2, kt1 = wv * 2 + 1;
    bool has1 = (kt1 < 7);

    // ---- B fragments from global (L2-hot): lane holds W[kt*16+l15][ks*32+quad*8 ..+7]
    short8 bh0[8], bl0[8], bh1[8], bl1[8];
    {
        const short8* ph0 = (const short8*)(wh + (kt0 * 16 + l15) * FF);
        const short8* pl0 = (const short8*)(wl + (kt0 * 16 + l15) * FF);
        int k1row = has1 ? (kt1 * 16 + l15) : 0;
        const short8* ph1 = (const short8*)(wh + k1row * FF);
        const short8* pl1 = (const short8*)(wl + k1row * FF);
#pragma unroll
        for (int ks = 0; ks < 8; ++ks) {
            bh0[ks] = ph0[ks * 4 + quad];
            bl0[ks] = pl0[ks * 4 + quad];
            bh1[ks] = ph1[ks * 4 + quad];
            bl1[ks] = pl1[ks * 4 + quad];
        }
    }

    // epilogue per-k constants (uniform over rows)
    int kout0 = kt0 * 16 + l15;
    int kout1 = has1 ? (kt1 * 16 + l15) : 0;
    float pd0 = pxd[(b * NN + i) * KP + kout0];
    float pd1 = pxd[(b * NN + i) * KP + kout1];
    float bb0 = b1p[kout0], bb1v = b1p[kout1];
    float w20 = w2p[kout0];
    float w21 = has1 ? w2p[kout1] : 0.f;

#pragma unroll
    for (int mt = 0; mt < 2; ++mt) {
        // A fragments from LDS
        short8 ah[8], al[8];
        {
            int arow = mt * 16 + l15;
            const short* base_h = &dth[0][0] + arow * AP;
            const short* base_l = &dtl[0][0] + arow * AP;
#pragma unroll
            for (int ks = 0; ks < 8; ++ks) {
                ah[ks] = *(const short8*)(base_h + ks * 32 + quad * 8);
                al[ks] = *(const short8*)(base_l + ks * 32 + quad * 8);
            }
        }
        f32x4 acc0 = {0.f, 0.f, 0.f, 0.f};
        f32x4 acc1 = {0.f, 0.f, 0.f, 0.f};
#pragma unroll
        for (int ks = 0; ks < 8; ++ks) {
            acc0 = __builtin_amdgcn_mfma_f32_16x16x32_bf16(ah[ks], bh0[ks], acc0, 0, 0, 0);
            acc0 = __builtin_amdgcn_mfma_f32_16x16x32_bf16(al[ks], bl0[ks], acc0, 0, 0, 0);
            if (has1) {
                acc1 = __builtin_amdgcn_mfma_f32_16x16x32_bf16(ah[ks], bh1[ks], acc1, 0, 0, 0);
                acc1 = __builtin_amdgcn_mfma_f32_16x16x32_bf16(al[ks], bl1[ks], acc1, 0, 0, 0);
            }
        }
        // epilogue: D[row=quad*4+r][col=l15]
#pragma unroll
        for (int r = 0; r < 4; ++r) {
            int m = mt * 16 + quad * 4 + r;
            int jg = jbase + m;
            int jc = (jg <= SS) ? jg : SS;
            float pe0 = pxe[(b * NN + jc) * KP + kout0];
            float pe1 = pxe[(b * NN + jc) * KP + kout1];
            float h0 = acc0[r] + pd0 + pe0 + bb0;
            float s = w20 * prelu_f(h0, a2);
            float h1 = acc1[r] + pd1 + pe1 + bb1v;
            s += w21 * prelu_f(h1, a2);
            s += __shfl_xor(s, 1);
            s += __shfl_xor(s, 2);
            s += __shfl_xor(s, 4);
            s += __shfl_xor(s, 8);
            if (l15 == 0) red[wv][m] = s;
        }
    }
    __syncthreads();
    if (tid < JT) {
        int jg = jbase + tid;
        if (jg <= SS) {
            float tot = red[0][tid] + red[1][tid] + red[2][tid] + red[3][tid] + b2p[0];
            scores[(b * NN + i) * NN + jg] = tot;
        }
    }
}

// ---------------- K6: cls / bin heads -------------------------------------
__global__ void k_heads(const float* __restrict__ rnn,
                        const float* __restrict__ ac1p, const float* __restrict__ Wc1,
                        const float* __restrict__ bc1, const float* __restrict__ ac2p,
                        const float* __restrict__ Wc2, const float* __restrict__ bc2,
                        const float* __restrict__ ab1p, const float* __restrict__ Wb1,
                        const float* __restrict__ bb1, const float* __restrict__ ab2p,
                        const float* __restrict__ Wb2, const float* __restrict__ bb2,
                        float* __restrict__ cls_out, float* __restrict__ bin_out) {
    int blk = blockIdx.x;           // b*S + t
    int ts = blk % SS, b = blk / SS;
    int tid = threadIdx.x;
    __shared__ __align__(16) float prc[FF], prb[FF];
    __shared__ __align__(16) float uc[KH], ub[KH];
    float ac1 = ac1p[0], ab1 = ab1p[0];
    for (int f = tid; f < FF; f += 128) {
        float rv = rnn[(b * SS + ts) * FF + f];
        prc[f] = prelu_f(rv, ac1);
        prb[f] = prelu_f(rv, ab1);
    }
    __syncthreads();
    if (tid < KH) {
        const float* wc = Wc1 + tid * FF;
        const float* wb = Wb1 + tid * FF;
        float ac = 0.f, ab = 0.f;
#pragma unroll 8
        for (int f = 0; f < FF; f += 4) {
            float4 c4 = *(const float4*)(wc + f);
            float4 b4 = *(const float4*)(wb + f);
            ac += c4.x * prc[f] + c4.y * prc[f + 1] + c4.z * prc[f + 2] + c4.w * prc[f + 3];
            ab += b4.x * prb[f] + b4.y * prb[f + 1] + b4.z * prb[f + 2] + b4.w * prb[f + 3];
        }
        uc[tid] = prelu_f(ac + bc1[tid], ac2p[0]);
        ub[tid] = prelu_f(ab + bb1[tid], ab2p[0]);
    }
    __syncthreads();
    if (tid < NCLS) {
        const float* w = Wc2 + tid * KH;
        float acc = bc2[tid];
#pragma unroll
        for (int q = 0; q < KH; q += 4) {
            float4 w4 = *(const float4*)(w + q);
            acc += w4.x * uc[q] + w4.y * uc[q + 1] + w4.z * uc[q + 2] + w4.w * uc[q + 3];
        }
        cls_out[(b * SS + ts) * NCLS + tid] = acc;
    }
    if (tid >= 64 && tid < 66) {
        int o = tid - 64;
        const float* w = Wb2 + o * KH;
        float acc = bb2[o];
#pragma unroll
        for (int q = 0; q < KH; q += 4) {
            float4 w4 = *(const float4*)(w + q);
            acc += w4.x * ub[q] + w4.y * ub[q + 1] + w4.z * ub[q + 2] + w4.w * ub[q + 3];
        }
        bin_out[(b * SS + ts) * 2 + o] = acc;
    }
}

// ---------------- K7: DP segment search -----------------------------------
__global__ void k_dp(const float* __restrict__ scores, const int* __restrict__ lengths,
                     float* __restrict__ predF, float* __restrict__ prevF) {
    int b = blockIdx.x;
    int lane = threadIdx.x;          // 64 threads, 1 wave
    __shared__ float bl[NN];
    for (int idx = lane; idx < NN; idx += 64) bl[idx] = 0.f;
    __syncthreads();
    if (lane == 0) prevF[b * NN] = 0.f;

    int lo = 0, cnt = 1;
    float sc = (lane < cnt) ? scores[(b * NN + lo + lane) * NN + 1] : 0.f;

    for (int i = 1; i <= NN - 1; ++i) {
        int myk = lo + lane;
        float cand = (lane < cnt) ? bl[myk] + sc : -INFINITY;
        int idx = myk;
        int lo2 = (i + 1 > MAXSEG) ? (i + 1 - MAXSEG) : 0;
        int cnt2 = i + 1 - lo2;
        float scn = 0.f;
        if (i + 1 <= NN - 1 && lane < cnt2)
            scn = scores[(b * NN + lo2 + lane) * NN + (i + 1)];
#pragma unroll
        for (int off = 32; off; off >>= 1) {
            float vo = __shfl_down(cand, off);
            int io = __shfl_down(idx, off);
            if (vo > cand || (vo == cand && io < idx)) { cand = vo; idx = io; }
        }
        if (lane == 0) {
            bl[i] = cand;
            prevF[b * NN + i] = (float)idx;
        }
        __syncthreads();
        sc = scn;
        lo = lo2; cnt = cnt2;
    }
    if (lane == 0) {
        int len = lengths[b];
        predF[b] = bl[len];
    }
}

// ---------------- launch ---------------------------------------------------
extern "C" void kernel_launch(void* const* d_in, const int* in_sizes, int n_in,
                              void* d_out, int out_size, void* d_ws, size_t ws_size,
                              hipStream_t stream) {
    const float* x    = (const float*)d_in[0];
    const int* lengths= (const int*)d_in[1];
    const float* Wi_f = (const float*)d_in[2];
    const float* Wh_f = (const float*)d_in[3];
    const float* b_f  = (const float*)d_in[4];
    const float* Wi_b = (const float*)d_in[5];
    const float* Wh_b = (const float*)d_in[6];
    const float* b_b  = (const float*)d_in[7];
    const float* a1   = (const float*)d_in[8];
    const float* W1   = (const float*)d_in[9];
    const float* b1   = (const float*)d_in[10];
    const float* a2   = (const float*)d_in[11];
    const float* W2   = (const float*)d_in[12];
    const float* b2   = (const float*)d_in[13];
    const float* ac1  = (const float*)d_in[14];
    const float* Wc1  = (const float*)d_in[15];
    const float* bc1  = (const float*)d_in[16];
    const float* ac2  = (const float*)d_in[17];
    const float* Wc2  = (const float*)d_in[18];
    const float* bc2  = (const float*)d_in[19];
    const float* ab1  = (const float*)d_in[20];
    const float* Wb1  = (const float*)d_in[21];
    const float* bb1  = (const float*)d_in[22];
    const float* ab2  = (const float*)d_in[23];
    const float* Wb2  = (const float*)d_in[24];
    const float* bb2  = (const float*)d_in[25];

    float* out = (float*)d_out;
    float* scores = out + SCORES_OFF;
    float* cls    = out + CLS_OFF;
    float* bin    = out + BIN_OFF;
    float* pred   = out + PRED_OFF;
    float* prev   = out + PREV_OFF;

    float* ws   = (float*)d_ws;
    float* gx   = ws + WS_GX;
    float* rnn  = ws + WS_RNN;
    float* cum  = ws + WS_CUM;
    float* pxd  = ws + WS_PXD;
    float* pxe  = ws + WS_PXE;
    float* part = ws + WS_PART;
    short* wH   = (short*)(ws + WS_WH);
    short* wL   = (short*)(ws + WS_WL);
    float* w2p  = ws + WS_W2P;
    float* b1p  = ws + WS_B1P;

    k_prep<<<KP, FF, 0, stream>>>(W1, W2, b1, wH, wL, w2p, b1p);
    k_lstm_pre<<<4 * SS, 256, 0, stream>>>(x, Wi_f, b_f, Wi_b, b_b, gx);
    k_lstm_rec<<<4, 512, 0, stream>>>(Wh_f, Wh_b, gx, rnn);
    k_cum_part<<<BB * NCH, FF, 0, stream>>>(rnn, part);
    k_cum_off<<<BB, FF, 0, stream>>>(part);
    k_cum_write<<<BB * NCH, FF, 0, stream>>>(rnn, part, cum);
    k_pxde<<<BB * NN, 256, 0, stream>>>(rnn, W1, a1, pxd, pxe);
    k_scores<<<BB * NN * JTILES, 256, 0, stream>>>(cum, wH, wL, pxd, pxe, b1p, w2p, b2,
                                                   a1, a2, scores);
    k_heads<<<BB * SS, 128, 0, stream>>>(rnn, ac1, Wc1, bc1, ac2, Wc2, bc2,
                                         ab1, Wb1, bb1, ab2, Wb2, bb2, cls, bin);
    k_dp<<<BB, 64, 0, stream>>>(scores, lengths, pred, prev);
}

// Round 3
// 1052.471 us; speedup vs baseline: 1.8962x; 1.1088x over previous
//
#include <hip/hip_runtime.h>
#include <math.h>

// Problem constants
#define BB 2
#define SS 400
#define II 80
#define HH 128
#define FF 256          // 2*H
#define NN 401          // S+1
#define G4 512          // 4*H
#define MAXSEG 50
#define NCLS 50
#define KH 100          // rows of W1 / Wc1 / Wb1
#define KP 112          // KH padded to 7*16 for MFMA

// d_out layout (floats): scores | cls | bin | pred | prev
#define SCORES_OFF 0
#define CLS_OFF    (BB*NN*NN)
#define BIN_OFF    (CLS_OFF + BB*SS*NCLS)
#define PRED_OFF   (BIN_OFF + BB*SS*2)
#define PREV_OFF   (PRED_OFF + BB)

// workspace layout (float slots)
#define WS_GX      0                          // 4*S*512 = 819200
#define WS_RNN     (WS_GX + 4*SS*G4)          // B*S*F
#define WS_CUM     (WS_RNN + BB*SS*FF)        // B*N*F
#define WS_PXD     (WS_CUM + BB*NN*FF)        // B*N*KP
#define WS_PXE     (WS_PXD + BB*NN*KP)
#define WS_PART    (WS_PXE + BB*NN*KP)        // B*16*F
#define WS_WH      (WS_PART + BB*16*FF)       // W1c hi bf16: KP*FF shorts
#define WS_WL      (WS_WH + (KP*FF)/2)
#define WS_W2P     (WS_WL + (KP*FF)/2)        // KP floats
#define WS_B1P     (WS_W2P + KP)              // KP floats

typedef __attribute__((ext_vector_type(8))) short short8;
typedef __attribute__((ext_vector_type(4))) float f32x4;

__device__ __forceinline__ float prelu_f(float x, float a) {
    return x >= 0.f ? x : a * x;
}
__device__ __forceinline__ unsigned short f2bf(float x) {
    union { float f; unsigned u; } v; v.f = x;
    unsigned r = v.u + 0x7fffu + ((v.u >> 16) & 1u);   // RNE
    return (unsigned short)(r >> 16);
}
__device__ __forceinline__ float bf2f(unsigned short h) {
    union { unsigned u; float f; } v; v.u = ((unsigned)h) << 16; return v.f;
}
__device__ __forceinline__ float fast_sigmoid(float x) {
    return 1.f / (1.f + __expf(-x));
}
__device__ __forceinline__ float fast_tanh(float x) {
    return 1.f - 2.f / (1.f + __expf(2.f * x));
}

// ---------------- K0: prep W1c bf16 hi/lo + padded W2/b1 -------------------
__global__ void k_prep(const float* __restrict__ W1, const float* __restrict__ W2,
                       const float* __restrict__ b1,
                       short* __restrict__ wh, short* __restrict__ wl,
                       float* __restrict__ w2p, float* __restrict__ b1p) {
    int k = blockIdx.x;        // 0..111
    int f = threadIdx.x;       // 0..255
    float w = (k < KH) ? W1[k * (3 * FF) + f] : 0.f;
    unsigned short hi = f2bf(w);
    unsigned short lo = f2bf(w - bf2f(hi));
    wh[k * FF + f] = (short)hi;
    wl[k * FF + f] = (short)lo;
    if (f == 0) {
        w2p[k] = (k < KH) ? W2[k] : 0.f;
        b1p[k] = (k < KH) ? b1[k] : 0.f;
    }
}

// ---------------- K1: gx[db][t][g] = b[g] + x[b, xt, :] . Wi[g, :] ---------
__global__ void k_lstm_pre(const float* __restrict__ x,
                           const float* __restrict__ Wi_f, const float* __restrict__ b_f,
                           const float* __restrict__ Wi_b, const float* __restrict__ b_b,
                           float* __restrict__ gx) {
    int blk = blockIdx.x;          // db*S + t
    int t = blk % SS;
    int db = blk / SS;             // dir*2 + b
    int b = db & 1, dir = db >> 1;
    const float* Wi = dir ? Wi_b : Wi_f;
    const float* bias = dir ? b_b : b_f;
    int xt = dir ? (SS - 1 - t) : t;

    __shared__ __align__(16) float xr[II];
    int tid = threadIdx.x;
    if (tid < II) xr[tid] = x[(b * SS + xt) * II + tid];
    __syncthreads();

    for (int g = tid; g < G4; g += 256) {
        const float* w = Wi + g * II;
        float acc = bias[g];
#pragma unroll
        for (int i = 0; i < II; i += 4) {
            float4 w4 = *(const float4*)(w + i);
            acc += w4.x * xr[i] + w4.y * xr[i + 1] + w4.z * xr[i + 2] + w4.w * xr[i + 3];
        }
        gx[(db * SS + t) * G4 + g] = acc;
    }
}

// ---------------- K2: recurrent LSTM, 4 blocks (dir,b), 512 threads --------
// thread = (gate-pair p = tid>>1, k-half = tid&1); gates {p, p+256};
// W rows in VGPRs; h read from LDS as 16 ds_read_b128 (2-way broadcast, free);
// 8 accumulators; pair-combine via shfl_xor(1).
__global__ __launch_bounds__(512, 2)
void k_lstm_rec(const float* __restrict__ Wh_f, const float* __restrict__ Wh_b,
                const float* __restrict__ gx, float* __restrict__ rnn_out) {
    int db = blockIdx.x;
    int b = db & 1, dir = db >> 1;
    const float* Wh = dir ? Wh_b : Wh_f;
    int tid = threadIdx.x;
    int p = tid >> 1;          // 0..255
    int half = tid & 1;        // which 64-wide k-slice
    int g0 = p, g1 = p + 256;
    int gw = half ? g1 : g0;   // gate this thread writes

    float4 w0[16], w1[16];
#pragma unroll
    for (int c = 0; c < 16; ++c) {
        w0[c] = *(const float4*)(Wh + g0 * HH + half * 64 + c * 4);
        w1[c] = *(const float4*)(Wh + g1 * HH + half * 64 + c * 4);
    }

    __shared__ __align__(16) float hs[HH];
    __shared__ float gsh[G4];
    if (tid < HH) hs[tid] = 0.f;
    float c_state = 0.f;
    __syncthreads();

    const float* gxp = gx + db * SS * G4;
    float gcur = gxp[gw];                      // prefetch step 0
    const float4* hs4 = (const float4*)hs;
    for (int step = 0; step < SS; ++step) {
        float gnext = (step + 1 < SS) ? gxp[(step + 1) * G4 + gw] : 0.f;
        float a0 = 0.f, a1 = 0.f, a2 = 0.f, a3 = 0.f;
        float c0 = 0.f, c1 = 0.f, c2 = 0.f, c3 = 0.f;
#pragma unroll
        for (int c = 0; c < 16; ++c) {
            float4 h4 = hs4[half * 16 + c];
            a0 += w0[c].x * h4.x; a1 += w0[c].y * h4.y;
            a2 += w0[c].z * h4.z; a3 += w0[c].w * h4.w;
            c0 += w1[c].x * h4.x; c1 += w1[c].y * h4.y;
            c2 += w1[c].z * h4.z; c3 += w1[c].w * h4.w;
        }
        float s0 = (a0 + a1) + (a2 + a3);
        float s1 = (c0 + c1) + (c2 + c3);
        s0 += __shfl_xor(s0, 1);
        s1 += __shfl_xor(s1, 1);
        gsh[gw] = (half ? s1 : s0) + gcur;
        __syncthreads();
        if (tid < HH) {
            float gi = gsh[tid], gf = gsh[HH + tid];
            float gg = gsh[2 * HH + tid], go = gsh[3 * HH + tid];
            float si = fast_sigmoid(gi);
            float sf = fast_sigmoid(gf);
            float so = fast_sigmoid(go);
            c_state = sf * c_state + si * fast_tanh(gg);
            float h = so * fast_tanh(c_state);
            hs[tid] = h;
            int xt = dir ? (SS - 1 - step) : step;
            rnn_out[(b * SS + xt) * FF + dir * HH + tid] = h;
        }
        __syncthreads();
        gcur = gnext;
    }
}

// ---------------- K3: cumsum over time (3 passes) --------------------------
#define CHUNK 25
#define NCH 16
__global__ void k_cum_part(const float* __restrict__ rnn, float* __restrict__ part) {
    int blk = blockIdx.x;           // b*NCH + c
    int c = blk % NCH, b = blk / NCH;
    int f = threadIdx.x;
    float s = 0.f;
    for (int r = 0; r < CHUNK; ++r) s += rnn[(b * SS + c * CHUNK + r) * FF + f];
    part[blk * FF + f] = s;
}
__global__ void k_cum_off(float* __restrict__ part) {
    int b = blockIdx.x;
    int f = threadIdx.x;
    float run = 0.f;
    for (int c = 0; c < NCH; ++c) {
        int idx = (b * NCH + c) * FF + f;
        float tmp = part[idx];
        part[idx] = run;
        run += tmp;
    }
}
__global__ void k_cum_write(const float* __restrict__ rnn, const float* __restrict__ part,
                            float* __restrict__ cum) {
    int blk = blockIdx.x;           // b*NCH + c
    int c = blk % NCH, b = blk / NCH;
    int f = threadIdx.x;
    float run = part[blk * FF + f];
    cum[(b * NN + c * CHUNK) * FF + f] = run;
    for (int idx = 1; idx <= CHUNK; ++idx) {
        run += rnn[(b * SS + c * CHUNK + idx - 1) * FF + f];
        cum[(b * NN + c * CHUNK + idx) * FF + f] = run;
    }
}

// ---------------- K4: pxd/pxe = prelu(xp,a1) @ W1d.T / W1e.T (stride KP) ---
__global__ void k_pxde(const float* __restrict__ rnn, const float* __restrict__ W1,
                       const float* __restrict__ a1p,
                       float* __restrict__ pxd, float* __restrict__ pxe) {
    int blk = blockIdx.x;           // b*N + n
    int n = blk % NN, b = blk / NN;
    int tid = threadIdx.x;
    float a1 = a1p[0];
    __shared__ __align__(16) float px[FF];
    float rv = (n == 0) ? 0.f : rnn[(b * SS + n - 1) * FF + tid];
    px[tid] = prelu_f(rv, a1);
    __syncthreads();

    if (tid < KH) {
        const float* w = W1 + tid * (3 * FF) + FF;    // W1d row
        float acc = 0.f;
#pragma unroll 8
        for (int f = 0; f < FF; f += 4) {
            float4 w4 = *(const float4*)(w + f);
            acc += w4.x * px[f] + w4.y * px[f + 1] + w4.z * px[f + 2] + w4.w * px[f + 3];
        }
        pxd[blk * KP + tid] = acc;
    } else if (tid >= KH && tid < KP) {
        pxd[blk * KP + tid] = 0.f;                    // pad
    } else if (tid >= 128 && tid < 128 + KH) {
        int k = tid - 128;
        const float* w = W1 + k * (3 * FF) + 2 * FF;  // W1e row
        float acc = 0.f;
#pragma unroll 8
        for (int f = 0; f < FF; f += 4) {
            float4 w4 = *(const float4*)(w + f);
            acc += w4.x * px[f] + w4.y * px[f + 1] + w4.z * px[f + 2] + w4.w * px[f + 3];
        }
        pxe[blk * KP + k] = acc;
    } else if (tid >= 128 + KH && tid < 128 + KP) {
        pxe[blk * KP + (tid - 128)] = 0.f;            // pad
    }
}

// ---------------- K5: scores via MFMA (bf16 hi/lo split A, bf16 W) ---------
#define JT 32
#define JTILES 13
#define AP 264          // row stride in shorts (256 + 8 pad)
__global__ __launch_bounds__(256, 2)
void k_scores(const float* __restrict__ cum,
              const short* __restrict__ wh, const short* __restrict__ wl,
              const float* __restrict__ pxd, const float* __restrict__ pxe,
              const float* __restrict__ b1p, const float* __restrict__ w2p,
              const float* __restrict__ b2p,
              const float* __restrict__ a1p, const float* __restrict__ a2p,
              float* __restrict__ scores) {
    int blk = blockIdx.x;
    int jt = blk % JTILES;
    int i = (blk / JTILES) % NN;
    int b = blk / (JTILES * NN);
    int tid = threadIdx.x;
    float a1 = a1p[0], a2 = a2p[0];
    int jbase = jt * JT;

    __shared__ __align__(16) float ci[FF];
    __shared__ __align__(16) short dth[JT][AP];
    __shared__ __align__(16) short dtl[JT][AP];
    __shared__ float red[4][JT];

    ci[tid] = cum[(b * NN + i) * FF + tid];
    __syncthreads();

    {
        int row = tid >> 3;
        int fb = (tid & 7) * 32;
        int jg = jbase + row;
        int jc = (jg <= SS) ? jg : SS;
        const float* cj = cum + (b * NN + jc) * FF + fb;
#pragma unroll
        for (int c8 = 0; c8 < 4; ++c8) {
            float4 v0 = *(const float4*)(cj + c8 * 8);
            float4 v1 = *(const float4*)(cj + c8 * 8 + 4);
            union { short8 s; unsigned short u[8]; } h8, l8;
            float dv[8] = { v0.x, v0.y, v0.z, v0.w, v1.x, v1.y, v1.z, v1.w };
#pragma unroll
            for (int e = 0; e < 8; ++e) {
                float d = prelu_f(dv[e] - ci[fb + c8 * 8 + e], a1);
                unsigned short hi = f2bf(d);
                h8.u[e] = hi;
                l8.u[e] = f2bf(d - bf2f(hi));
            }
            *(short8*)(&dth[row][fb + c8 * 8]) = h8.s;
            *(short8*)(&dtl[row][fb + c8 * 8]) = l8.s;
        }
    }
    __syncthreads();

    int lane = tid & 63;
    int wv = tid >> 6;
    int quad = lane >> 4;
    int l15 = lane & 15;
    int kt0 = wv * 2, kt1 = wv * 2 + 1;
    bool has1 = (kt1 < 7);

    short8 bh0[8], bl0[8], bh1[8], bl1[8];
    {
        const short8* ph0 = (const short8*)(wh + (kt0 * 16 + l15) * FF);
        const short8* pl0 = (const short8*)(wl + (kt0 * 16 + l15) * FF);
        int k1row = has1 ? (kt1 * 16 + l15) : 0;
        const short8* ph1 = (const short8*)(wh + k1row * FF);
        const short8* pl1 = (const short8*)(wl + k1row * FF);
#pragma unroll
        for (int ks = 0; ks < 8; ++ks) {
            bh0[ks] = ph0[ks * 4 + quad];
            bl0[ks] = pl0[ks * 4 + quad];
            bh1[ks] = ph1[ks * 4 + quad];
            bl1[ks] = pl1[ks * 4 + quad];
        }
    }

    int kout0 = kt0 * 16 + l15;
    int kout1 = has1 ? (kt1 * 16 + l15) : 0;
    float pd0 = pxd[(b * NN + i) * KP + kout0];
    float pd1 = pxd[(b * NN + i) * KP + kout1];
    float bb0 = b1p[kout0], bb1v = b1p[kout1];
    float w20 = w2p[kout0];
    float w21 = has1 ? w2p[kout1] : 0.f;

#pragma unroll
    for (int mt = 0; mt < 2; ++mt) {
        short8 ah[8], al[8];
        {
            int arow = mt * 16 + l15;
            const short* base_h = &dth[0][0] + arow * AP;
            const short* base_l = &dtl[0][0] + arow * AP;
#pragma unroll
            for (int ks = 0; ks < 8; ++ks) {
                ah[ks] = *(const short8*)(base_h + ks * 32 + quad * 8);
                al[ks] = *(const short8*)(base_l + ks * 32 + quad * 8);
            }
        }
        f32x4 acc0 = {0.f, 0.f, 0.f, 0.f};
        f32x4 acc1 = {0.f, 0.f, 0.f, 0.f};
#pragma unroll
        for (int ks = 0; ks < 8; ++ks) {
            acc0 = __builtin_amdgcn_mfma_f32_16x16x32_bf16(ah[ks], bh0[ks], acc0, 0, 0, 0);
            acc0 = __builtin_amdgcn_mfma_f32_16x16x32_bf16(al[ks], bl0[ks], acc0, 0, 0, 0);
            if (has1) {
                acc1 = __builtin_amdgcn_mfma_f32_16x16x32_bf16(ah[ks], bh1[ks], acc1, 0, 0, 0);
                acc1 = __builtin_amdgcn_mfma_f32_16x16x32_bf16(al[ks], bl1[ks], acc1, 0, 0, 0);
            }
        }
#pragma unroll
        for (int r = 0; r < 4; ++r) {
            int m = mt * 16 + quad * 4 + r;
            int jg = jbase + m;
            int jc = (jg <= SS) ? jg : SS;
            float pe0 = pxe[(b * NN + jc) * KP + kout0];
            float pe1 = pxe[(b * NN + jc) * KP + kout1];
            float h0 = acc0[r] + pd0 + pe0 + bb0;
            float s = w20 * prelu_f(h0, a2);
            float h1 = acc1[r] + pd1 + pe1 + bb1v;
            s += w21 * prelu_f(h1, a2);
            s += __shfl_xor(s, 1);
            s += __shfl_xor(s, 2);
            s += __shfl_xor(s, 4);
            s += __shfl_xor(s, 8);
            if (l15 == 0) red[wv][m] = s;
        }
    }
    __syncthreads();
    if (tid < JT) {
        int jg = jbase + tid;
        if (jg <= SS) {
            float tot = red[0][tid] + red[1][tid] + red[2][tid] + red[3][tid] + b2p[0];
            scores[(b * NN + i) * NN + jg] = tot;
        }
    }
}

// ---------------- K6: cls / bin heads -------------------------------------
__global__ void k_heads(const float* __restrict__ rnn,
                        const float* __restrict__ ac1p, const float* __restrict__ Wc1,
                        const float* __restrict__ bc1, const float* __restrict__ ac2p,
                        const float* __restrict__ Wc2, const float* __restrict__ bc2,
                        const float* __restrict__ ab1p, const float* __restrict__ Wb1,
                        const float* __restrict__ bb1, const float* __restrict__ ab2p,
                        const float* __restrict__ Wb2, const float* __restrict__ bb2,
                        float* __restrict__ cls_out, float* __restrict__ bin_out) {
    int blk = blockIdx.x;           // b*S + t
    int ts = blk % SS, b = blk / SS;
    int tid = threadIdx.x;
    __shared__ __align__(16) float prc[FF], prb[FF];
    __shared__ __align__(16) float uc[KH], ub[KH];
    float ac1 = ac1p[0], ab1 = ab1p[0];
    for (int f = tid; f < FF; f += 128) {
        float rv = rnn[(b * SS + ts) * FF + f];
        prc[f] = prelu_f(rv, ac1);
        prb[f] = prelu_f(rv, ab1);
    }
    __syncthreads();
    if (tid < KH) {
        const float* wc = Wc1 + tid * FF;
        const float* wb = Wb1 + tid * FF;
        float ac = 0.f, ab = 0.f;
#pragma unroll 8
        for (int f = 0; f < FF; f += 4) {
            float4 c4 = *(const float4*)(wc + f);
            float4 b4 = *(const float4*)(wb + f);
            ac += c4.x * prc[f] + c4.y * prc[f + 1] + c4.z * prc[f + 2] + c4.w * prc[f + 3];
            ab += b4.x * prb[f] + b4.y * prb[f + 1] + b4.z * prb[f + 2] + b4.w * prb[f + 3];
        }
        uc[tid] = prelu_f(ac + bc1[tid], ac2p[0]);
        ub[tid] = prelu_f(ab + bb1[tid], ab2p[0]);
    }
    __syncthreads();
    if (tid < NCLS) {
        const float* w = Wc2 + tid * KH;
        float acc = bc2[tid];
#pragma unroll
        for (int q = 0; q < KH; q += 4) {
            float4 w4 = *(const float4*)(w + q);
            acc += w4.x * uc[q] + w4.y * uc[q + 1] + w4.z * uc[q + 2] + w4.w * uc[q + 3];
        }
        cls_out[(b * SS + ts) * NCLS + tid] = acc;
    }
    if (tid >= 64 && tid < 66) {
        int o = tid - 64;
        const float* w = Wb2 + o * KH;
        float acc = bb2[o];
#pragma unroll
        for (int q = 0; q < KH; q += 4) {
            float4 w4 = *(const float4*)(w + q);
            acc += w4.x * ub[q] + w4.y * ub[q + 1] + w4.z * ub[q + 2] + w4.w * ub[q + 3];
        }
        bin_out[(b * SS + ts) * 2 + o] = acc;
    }
}

// ---------------- K7: DP segment search -----------------------------------
__global__ void k_dp(const float* __restrict__ scores, const int* __restrict__ lengths,
                     float* __restrict__ predF, float* __restrict__ prevF) {
    int b = blockIdx.x;
    int lane = threadIdx.x;          // 64 threads, 1 wave
    __shared__ float bl[NN];
    for (int idx = lane; idx < NN; idx += 64) bl[idx] = 0.f;
    __syncthreads();
    if (lane == 0) prevF[b * NN] = 0.f;

    int lo = 0, cnt = 1;
    float sc = (lane < cnt) ? scores[(b * NN + lo + lane) * NN + 1] : 0.f;

    for (int i = 1; i <= NN - 1; ++i) {
        int myk = lo + lane;
        float cand = (lane < cnt) ? bl[myk] + sc : -INFINITY;
        int idx = myk;
        int lo2 = (i + 1 > MAXSEG) ? (i + 1 - MAXSEG) : 0;
        int cnt2 = i + 1 - lo2;
        float scn = 0.f;
        if (i + 1 <= NN - 1 && lane < cnt2)
            scn = scores[(b * NN + lo2 + lane) * NN + (i + 1)];
#pragma unroll
        for (int off = 32; off; off >>= 1) {
            float vo = __shfl_down(cand, off);
            int io = __shfl_down(idx, off);
            if (vo > cand || (vo == cand && io < idx)) { cand = vo; idx = io; }
        }
        if (lane == 0) {
            bl[i] = cand;
            prevF[b * NN + i] = (float)idx;
        }
        __syncthreads();
        sc = scn;
        lo = lo2; cnt = cnt2;
    }
    if (lane == 0) {
        int len = lengths[b];
        predF[b] = bl[len];
    }
}

// ---------------- launch ---------------------------------------------------
extern "C" void kernel_launch(void* const* d_in, const int* in_sizes, int n_in,
                              void* d_out, int out_size, void* d_ws, size_t ws_size,
                              hipStream_t stream) {
    const float* x    = (const float*)d_in[0];
    const int* lengths= (const int*)d_in[1];
    const float* Wi_f = (const float*)d_in[2];
    const float* Wh_f = (const float*)d_in[3];
    const float* b_f  = (const float*)d_in[4];
    const float* Wi_b = (const float*)d_in[5];
    const float* Wh_b = (const float*)d_in[6];
    const float* b_b  = (const float*)d_in[7];
    const float* a1   = (const float*)d_in[8];
    const float* W1   = (const float*)d_in[9];
    const float* b1   = (const float*)d_in[10];
    const float* a2   = (const float*)d_in[11];
    const float* W2   = (const float*)d_in[12];
    const float* b2   = (const float*)d_in[13];
    const float* ac1  = (const float*)d_in[14];
    const float* Wc1  = (const float*)d_in[15];
    const float* bc1  = (const float*)d_in[16];
    const float* ac2  = (const float*)d_in[17];
    const float* Wc2  = (const float*)d_in[18];
    const float* bc2  = (const float*)d_in[19];
    const float* ab1  = (const float*)d_in[20];
    const float* Wb1  = (const float*)d_in[21];
    const float* bb1  = (const float*)d_in[22];
    const float* ab2  = (const float*)d_in[23];
    const float* Wb2  = (const float*)d_in[24];
    const float* bb2  = (const float*)d_in[25];

    float* out = (float*)d_out;
    float* scores = out + SCORES_OFF;
    float* cls    = out + CLS_OFF;
    float* bin    = out + BIN_OFF;
    float* pred   = out + PRED_OFF;
    float* prev   = out + PREV_OFF;

    float* ws   = (float*)d_ws;
    float* gx   = ws + WS_GX;
    float* rnn  = ws + WS_RNN;
    float* cum  = ws + WS_CUM;
    float* pxd  = ws + WS_PXD;
    float* pxe  = ws + WS_PXE;
    float* part = ws + WS_PART;
    short* wH   = (short*)(ws + WS_WH);
    short* wL   = (short*)(ws + WS_WL);
    float* w2p  = ws + WS_W2P;
    float* b1p  = ws + WS_B1P;

    k_prep<<<KP, FF, 0, stream>>>(W1, W2, b1, wH, wL, w2p, b1p);
    k_lstm_pre<<<4 * SS, 256, 0, stream>>>(x, Wi_f, b_f, Wi_b, b_b, gx);
    k_lstm_rec<<<4, 512, 0, stream>>>(Wh_f, Wh_b, gx, rnn);
    k_cum_part<<<BB * NCH, FF, 0, stream>>>(rnn, part);
    k_cum_off<<<BB, FF, 0, stream>>>(part);
    k_cum_write<<<BB * NCH, FF, 0, stream>>>(rnn, part, cum);
    k_pxde<<<BB * NN, 256, 0, stream>>>(rnn, W1, a1, pxd, pxe);
    k_scores<<<BB * NN * JTILES, 256, 0, stream>>>(cum, wH, wL, pxd, pxe, b1p, w2p, b2,
                                                   a1, a2, scores);
    k_heads<<<BB * SS, 128, 0, stream>>>(rnn, ac1, Wc1, bc1, ac2, Wc2, bc2,
                                         ab1, Wb1, bb1, ab2, Wb2, bb2, cls, bin);
    k_dp<<<BB, 64, 0, stream>>>(scores, lengths, pred, prev);
}

// Round 4
// 1030.797 us; speedup vs baseline: 1.9361x; 1.0210x over previous
//
#include <hip/hip_runtime.h>
#include <math.h>

// Problem constants
#define BB 2
#define SS 400
#define II 80
#define HH 128
#define FF 256          // 2*H
#define NN 401          // S+1
#define G4 512          // 4*H
#define MAXSEG 50
#define NCLS 50
#define KH 100          // rows of W1 / Wc1 / Wb1
#define KP 112          // KH padded to 7*16 for MFMA

// d_out layout (floats): scores | cls | bin | pred | prev
#define SCORES_OFF 0
#define CLS_OFF    (BB*NN*NN)
#define BIN_OFF    (CLS_OFF + BB*SS*NCLS)
#define PRED_OFF   (BIN_OFF + BB*SS*2)
#define PREV_OFF   (PRED_OFF + BB)

// workspace layout (float slots)
#define WS_GX      0                          // 4*S*512 = 819200 (dead after k_lstm_rec;
                                              // reused as scoresT: BB*NN*NN = 321602)
#define WS_RNN     (WS_GX + 4*SS*G4)          // B*S*F
#define WS_CUM     (WS_RNN + BB*SS*FF)        // B*N*F
#define WS_PXD     (WS_CUM + BB*NN*FF)        // B*N*KP
#define WS_PXE     (WS_PXD + BB*NN*KP)
#define WS_PART    (WS_PXE + BB*NN*KP)        // B*16*F
#define WS_WH      (WS_PART + BB*16*FF)       // W1c hi bf16: KP*FF shorts
#define WS_WL      (WS_WH + (KP*FF)/2)
#define WS_W2P     (WS_WL + (KP*FF)/2)        // KP floats
#define WS_B1P     (WS_W2P + KP)              // KP floats

typedef __attribute__((ext_vector_type(8))) short short8;
typedef __attribute__((ext_vector_type(4))) float f32x4;

__device__ __forceinline__ float prelu_f(float x, float a) {
    return x >= 0.f ? x : a * x;
}
__device__ __forceinline__ unsigned short f2bf(float x) {
    union { float f; unsigned u; } v; v.f = x;
    unsigned r = v.u + 0x7fffu + ((v.u >> 16) & 1u);   // RNE
    return (unsigned short)(r >> 16);
}
__device__ __forceinline__ float bf2f(unsigned short h) {
    union { unsigned u; float f; } v; v.u = ((unsigned)h) << 16; return v.f;
}
__device__ __forceinline__ float fast_sigmoid(float x) {
    return 1.f / (1.f + __expf(-x));
}
__device__ __forceinline__ float fast_tanh(float x) {
    return 1.f - 2.f / (1.f + __expf(2.f * x));
}

// ---------------- K0: prep W1c bf16 hi/lo + padded W2/b1 -------------------
__global__ void k_prep(const float* __restrict__ W1, const float* __restrict__ W2,
                       const float* __restrict__ b1,
                       short* __restrict__ wh, short* __restrict__ wl,
                       float* __restrict__ w2p, float* __restrict__ b1p) {
    int k = blockIdx.x;        // 0..111
    int f = threadIdx.x;       // 0..255
    float w = (k < KH) ? W1[k * (3 * FF) + f] : 0.f;
    unsigned short hi = f2bf(w);
    unsigned short lo = f2bf(w - bf2f(hi));
    wh[k * FF + f] = (short)hi;
    wl[k * FF + f] = (short)lo;
    if (f == 0) {
        w2p[k] = (k < KH) ? W2[k] : 0.f;
        b1p[k] = (k < KH) ? b1[k] : 0.f;
    }
}

// ---------------- K1: gx[db][t][g] = b[g] + x[b, xt, :] . Wi[g, :] ---------
__global__ void k_lstm_pre(const float* __restrict__ x,
                           const float* __restrict__ Wi_f, const float* __restrict__ b_f,
                           const float* __restrict__ Wi_b, const float* __restrict__ b_b,
                           float* __restrict__ gx) {
    int blk = blockIdx.x;          // db*S + t
    int t = blk % SS;
    int db = blk / SS;             // dir*2 + b
    int b = db & 1, dir = db >> 1;
    const float* Wi = dir ? Wi_b : Wi_f;
    const float* bias = dir ? b_b : b_f;
    int xt = dir ? (SS - 1 - t) : t;

    __shared__ __align__(16) float xr[II];
    int tid = threadIdx.x;
    if (tid < II) xr[tid] = x[(b * SS + xt) * II + tid];
    __syncthreads();

    for (int g = tid; g < G4; g += 256) {
        const float* w = Wi + g * II;
        float acc = bias[g];
#pragma unroll
        for (int i = 0; i < II; i += 4) {
            float4 w4 = *(const float4*)(w + i);
            acc += w4.x * xr[i] + w4.y * xr[i + 1] + w4.z * xr[i + 2] + w4.w * xr[i + 3];
        }
        gx[(db * SS + t) * G4 + g] = acc;
    }
}

// ---------------- K2: recurrent LSTM, 4 blocks (dir,b), 512 threads --------
// thread = (wave w, octet q, slice s): partials for 8 gates (2 units × i,f,g,o)
// over k-slice [s*16, s*16+16); butterfly-reduce over s (7 shfl) so lane s ends
// with gate gl=s; activations computed by all lanes; 3-shfl gather; lanes s%4==0
// own c-state for unit u0+(s>>2). h double-buffered in padded LDS (stride 20
// floats per 16-slice -> conflict-free). ONE barrier per step.
__global__ __launch_bounds__(512, 2)
void k_lstm_rec(const float* __restrict__ Wh_f, const float* __restrict__ Wh_b,
                const float* __restrict__ gx, float* __restrict__ rnn_out) {
    int db = blockIdx.x;
    int b = db & 1, dir = db >> 1;
    const float* Wh = dir ? Wh_b : Wh_f;
    int tid = threadIdx.x;
    int w = tid >> 6;
    int l = tid & 63;
    int q = l >> 3;
    int s = l & 7;
    int u0 = (w * 8 + q) * 2;
    int kbase = s * 16;

    // weights: 8 gates (gl = (usel<<2)|type) x 16 k -> 128 VGPRs
    float4 wv[8][4];
#pragma unroll
    for (int gl = 0; gl < 8; ++gl) {
        int gid = (gl & 3) * 128 + u0 + (gl >> 2);
        const float* wr = Wh + gid * HH + kbase;
#pragma unroll
        for (int c = 0; c < 4; ++c) wv[gl][c] = *(const float4*)(wr + c * 4);
    }

    int mygid = (s & 3) * 128 + u0 + (s >> 2);   // gate this lane ends up holding
    int myunit = u0 + (s >> 2);
    bool is_lead = (s & 3) == 0;

    __shared__ __align__(16) float hsp[2][8 * 20];   // 2 buffers, padded slices
    for (int i = tid; i < 2 * 160; i += 512) (&hsp[0][0])[i] = 0.f;
    float c_state = 0.f;
    __syncthreads();

    const float* gxp = gx + db * SS * G4;
    float gcur = gxp[mygid];                   // prefetch step 0
    int pb = 0;
    for (int step = 0; step < SS; ++step) {
        float gnext = (step + 1 < SS) ? gxp[(step + 1) * G4 + mygid] : 0.f;
        float4 h0 = *(const float4*)(&hsp[pb][s * 20]);
        float4 h1 = *(const float4*)(&hsp[pb][s * 20 + 4]);
        float4 h2 = *(const float4*)(&hsp[pb][s * 20 + 8]);
        float4 h3 = *(const float4*)(&hsp[pb][s * 20 + 12]);
        float v[8];
#pragma unroll
        for (int gl = 0; gl < 8; ++gl) {
            float4 wa = wv[gl][0], wb = wv[gl][1], wc = wv[gl][2], wd = wv[gl][3];
            float p0 = wa.x * h0.x + wa.y * h0.y + wa.z * h0.z + wa.w * h0.w;
            float p1 = wb.x * h1.x + wb.y * h1.y + wb.z * h1.z + wb.w * h1.w;
            float p2 = wc.x * h2.x + wc.y * h2.y + wc.z * h2.z + wc.w * h2.w;
            float p3 = wd.x * h3.x + wd.y * h3.y + wd.z * h3.z + wd.w * h3.w;
            v[gl] = (p0 + p1) + (p2 + p3);
        }
        // butterfly over s: lane s ends with full sum for gl = s
        float u4[4];
#pragma unroll
        for (int j = 0; j < 4; ++j) {
            float snd = (s & 4) ? v[j] : v[j + 4];
            float kp  = (s & 4) ? v[j + 4] : v[j];
            u4[j] = kp + __shfl_xor(snd, 4);
        }
        float u2[2];
#pragma unroll
        for (int j = 0; j < 2; ++j) {
            float snd = (s & 2) ? u4[j] : u4[j + 2];
            float kp  = (s & 2) ? u4[j + 2] : u4[j];
            u2[j] = kp + __shfl_xor(snd, 2);
        }
        {
            float snd = (s & 1) ? u2[0] : u2[1];
            float kp  = (s & 1) ? u2[1] : u2[0];
            float gate = kp + __shfl_xor(snd, 1) + gcur;
            // activation: type = s&3 (0=i,1=f,2=g,3=o)
            float act = ((s & 3) == 2) ? fast_tanh(gate) : fast_sigmoid(gate);
            float r1 = __shfl_xor(act, 1);   // lead: sigma(f)
            float p0 = __shfl_xor(act, 2);   // lead: tanh(g)
            float p1 = __shfl_xor(r1, 2);    // lead: sigma(o)
            if (is_lead) {
                c_state = r1 * c_state + act * p0;
                float h = p1 * fast_tanh(c_state);
                hsp[pb ^ 1][(myunit >> 4) * 20 + (myunit & 15)] = h;
                int xt = dir ? (SS - 1 - step) : step;
                rnn_out[(b * SS + xt) * FF + dir * HH + myunit] = h;
            }
        }
        __syncthreads();
        pb ^= 1;
        gcur = gnext;
    }
}

// ---------------- K3: cumsum over time (3 passes) --------------------------
#define CHUNK 25
#define NCH 16
__global__ void k_cum_part(const float* __restrict__ rnn, float* __restrict__ part) {
    int blk = blockIdx.x;           // b*NCH + c
    int c = blk % NCH, b = blk / NCH;
    int f = threadIdx.x;
    float s = 0.f;
    for (int r = 0; r < CHUNK; ++r) s += rnn[(b * SS + c * CHUNK + r) * FF + f];
    part[blk * FF + f] = s;
}
__global__ void k_cum_off(float* __restrict__ part) {
    int b = blockIdx.x;
    int f = threadIdx.x;
    float run = 0.f;
    for (int c = 0; c < NCH; ++c) {
        int idx = (b * NCH + c) * FF + f;
        float tmp = part[idx];
        part[idx] = run;
        run += tmp;
    }
}
__global__ void k_cum_write(const float* __restrict__ rnn, const float* __restrict__ part,
                            float* __restrict__ cum) {
    int blk = blockIdx.x;           // b*NCH + c
    int c = blk % NCH, b = blk / NCH;
    int f = threadIdx.x;
    float run = part[blk * FF + f];
    cum[(b * NN + c * CHUNK) * FF + f] = run;
    for (int idx = 1; idx <= CHUNK; ++idx) {
        run += rnn[(b * SS + c * CHUNK + idx - 1) * FF + f];
        cum[(b * NN + c * CHUNK + idx) * FF + f] = run;
    }
}

// ---------------- K4: pxd/pxe = prelu(xp,a1) @ W1d.T / W1e.T (stride KP) ---
__global__ void k_pxde(const float* __restrict__ rnn, const float* __restrict__ W1,
                       const float* __restrict__ a1p,
                       float* __restrict__ pxd, float* __restrict__ pxe) {
    int blk = blockIdx.x;           // b*N + n
    int n = blk % NN, b = blk / NN;
    int tid = threadIdx.x;
    float a1 = a1p[0];
    __shared__ __align__(16) float px[FF];
    float rv = (n == 0) ? 0.f : rnn[(b * SS + n - 1) * FF + tid];
    px[tid] = prelu_f(rv, a1);
    __syncthreads();

    if (tid < KH) {
        const float* w = W1 + tid * (3 * FF) + FF;    // W1d row
        float acc = 0.f;
#pragma unroll 8
        for (int f = 0; f < FF; f += 4) {
            float4 w4 = *(const float4*)(w + f);
            acc += w4.x * px[f] + w4.y * px[f + 1] + w4.z * px[f + 2] + w4.w * px[f + 3];
        }
        pxd[blk * KP + tid] = acc;
    } else if (tid >= KH && tid < KP) {
        pxd[blk * KP + tid] = 0.f;                    // pad
    } else if (tid >= 128 && tid < 128 + KH) {
        int k = tid - 128;
        const float* w = W1 + k * (3 * FF) + 2 * FF;  // W1e row
        float acc = 0.f;
#pragma unroll 8
        for (int f = 0; f < FF; f += 4) {
            float4 w4 = *(const float4*)(w + f);
            acc += w4.x * px[f] + w4.y * px[f + 1] + w4.z * px[f + 2] + w4.w * px[f + 3];
        }
        pxe[blk * KP + k] = acc;
    } else if (tid >= 128 + KH && tid < 128 + KP) {
        pxe[blk * KP + (tid - 128)] = 0.f;            // pad
    }
}

// ---------------- K5: scores via MFMA (bf16 hi/lo split A, bf16 W) ---------
#define JT 32
#define JTILES 13
#define AP 264          // row stride in shorts (256 + 8 pad)
__global__ __launch_bounds__(256, 2)
void k_scores(const float* __restrict__ cum,
              const short* __restrict__ wh, const short* __restrict__ wl,
              const float* __restrict__ pxd, const float* __restrict__ pxe,
              const float* __restrict__ b1p, const float* __restrict__ w2p,
              const float* __restrict__ b2p,
              const float* __restrict__ a1p, const float* __restrict__ a2p,
              float* __restrict__ scores, float* __restrict__ scoresT) {
    int blk = blockIdx.x;
    int jt = blk % JTILES;
    int i = (blk / JTILES) % NN;
    int b = blk / (JTILES * NN);
    int tid = threadIdx.x;
    float a1 = a1p[0], a2 = a2p[0];
    int jbase = jt * JT;

    __shared__ __align__(16) float ci[FF];
    __shared__ __align__(16) short dth[JT][AP];
    __shared__ __align__(16) short dtl[JT][AP];
    __shared__ float red[4][JT];

    ci[tid] = cum[(b * NN + i) * FF + tid];
    __syncthreads();

    {
        int row = tid >> 3;
        int fb = (tid & 7) * 32;
        int jg = jbase + row;
        int jc = (jg <= SS) ? jg : SS;
        const float* cj = cum + (b * NN + jc) * FF + fb;
#pragma unroll
        for (int c8 = 0; c8 < 4; ++c8) {
            float4 v0 = *(const float4*)(cj + c8 * 8);
            float4 v1 = *(const float4*)(cj + c8 * 8 + 4);
            union { short8 s; unsigned short u[8]; } h8, l8;
            float dv[8] = { v0.x, v0.y, v0.z, v0.w, v1.x, v1.y, v1.z, v1.w };
#pragma unroll
            for (int e = 0; e < 8; ++e) {
                float d = prelu_f(dv[e] - ci[fb + c8 * 8 + e], a1);
                unsigned short hi = f2bf(d);
                h8.u[e] = hi;
                l8.u[e] = f2bf(d - bf2f(hi));
            }
            *(short8*)(&dth[row][fb + c8 * 8]) = h8.s;
            *(short8*)(&dtl[row][fb + c8 * 8]) = l8.s;
        }
    }
    __syncthreads();

    int lane = tid & 63;
    int wv = tid >> 6;
    int quad = lane >> 4;
    int l15 = lane & 15;
    int kt0 = wv * 2, kt1 = wv * 2 + 1;
    bool has1 = (kt1 < 7);

    short8 bh0[8], bl0[8], bh1[8], bl1[8];
    {
        const short8* ph0 = (const short8*)(wh + (kt0 * 16 + l15) * FF);
        const short8* pl0 = (const short8*)(wl + (kt0 * 16 + l15) * FF);
        int k1row = has1 ? (kt1 * 16 + l15) : 0;
        const short8* ph1 = (const short8*)(wh + k1row * FF);
        const short8* pl1 = (const short8*)(wl + k1row * FF);
#pragma unroll
        for (int ks = 0; ks < 8; ++ks) {
            bh0[ks] = ph0[ks * 4 + quad];
            bl0[ks] = pl0[ks * 4 + quad];
            bh1[ks] = ph1[ks * 4 + quad];
            bl1[ks] = pl1[ks * 4 + quad];
        }
    }

    int kout0 = kt0 * 16 + l15;
    int kout1 = has1 ? (kt1 * 16 + l15) : 0;
    float pd0 = pxd[(b * NN + i) * KP + kout0];
    float pd1 = pxd[(b * NN + i) * KP + kout1];
    float bb0 = b1p[kout0], bb1v = b1p[kout1];
    float w20 = w2p[kout0];
    float w21 = has1 ? w2p[kout1] : 0.f;

#pragma unroll
    for (int mt = 0; mt < 2; ++mt) {
        short8 ah[8], al[8];
        {
            int arow = mt * 16 + l15;
            const short* base_h = &dth[0][0] + arow * AP;
            const short* base_l = &dtl[0][0] + arow * AP;
#pragma unroll
            for (int ks = 0; ks < 8; ++ks) {
                ah[ks] = *(const short8*)(base_h + ks * 32 + quad * 8);
                al[ks] = *(const short8*)(base_l + ks * 32 + quad * 8);
            }
        }
        f32x4 acc0 = {0.f, 0.f, 0.f, 0.f};
        f32x4 acc1 = {0.f, 0.f, 0.f, 0.f};
#pragma unroll
        for (int ks = 0; ks < 8; ++ks) {
            acc0 = __builtin_amdgcn_mfma_f32_16x16x32_bf16(ah[ks], bh0[ks], acc0, 0, 0, 0);
            acc0 = __builtin_amdgcn_mfma_f32_16x16x32_bf16(al[ks], bl0[ks], acc0, 0, 0, 0);
            if (has1) {
                acc1 = __builtin_amdgcn_mfma_f32_16x16x32_bf16(ah[ks], bh1[ks], acc1, 0, 0, 0);
                acc1 = __builtin_amdgcn_mfma_f32_16x16x32_bf16(al[ks], bl1[ks], acc1, 0, 0, 0);
            }
        }
#pragma unroll
        for (int r = 0; r < 4; ++r) {
            int m = mt * 16 + quad * 4 + r;
            int jg = jbase + m;
            int jc = (jg <= SS) ? jg : SS;
            float pe0 = pxe[(b * NN + jc) * KP + kout0];
            float pe1 = pxe[(b * NN + jc) * KP + kout1];
            float h0 = acc0[r] + pd0 + pe0 + bb0;
            float s = w20 * prelu_f(h0, a2);
            float h1 = acc1[r] + pd1 + pe1 + bb1v;
            s += w21 * prelu_f(h1, a2);
            s += __shfl_xor(s, 1);
            s += __shfl_xor(s, 2);
            s += __shfl_xor(s, 4);
            s += __shfl_xor(s, 8);
            if (l15 == 0) red[wv][m] = s;
        }
    }
    __syncthreads();
    if (tid < JT) {
        int jg = jbase + tid;
        if (jg <= SS) {
            float tot = red[0][tid] + red[1][tid] + red[2][tid] + red[3][tid] + b2p[0];
            scores[(b * NN + i) * NN + jg] = tot;
            scoresT[(b * NN + jg) * NN + i] = tot;   // transposed copy for k_dp
        }
    }
}

// ---------------- K6: cls / bin heads -------------------------------------
__global__ void k_heads(const float* __restrict__ rnn,
                        const float* __restrict__ ac1p, const float* __restrict__ Wc1,
                        const float* __restrict__ bc1, const float* __restrict__ ac2p,
                        const float* __restrict__ Wc2, const float* __restrict__ bc2,
                        const float* __restrict__ ab1p, const float* __restrict__ Wb1,
                        const float* __restrict__ bb1, const float* __restrict__ ab2p,
                        const float* __restrict__ Wb2, const float* __restrict__ bb2,
                        float* __restrict__ cls_out, float* __restrict__ bin_out) {
    int blk = blockIdx.x;           // b*S + t
    int ts = blk % SS, b = blk / SS;
    int tid = threadIdx.x;
    __shared__ __align__(16) float prc[FF], prb[FF];
    __shared__ __align__(16) float uc[KH], ub[KH];
    float ac1 = ac1p[0], ab1 = ab1p[0];
    for (int f = tid; f < FF; f += 128) {
        float rv = rnn[(b * SS + ts) * FF + f];
        prc[f] = prelu_f(rv, ac1);
        prb[f] = prelu_f(rv, ab1);
    }
    __syncthreads();
    if (tid < KH) {
        const float* wc = Wc1 + tid * FF;
        const float* wb = Wb1 + tid * FF;
        float ac = 0.f, ab = 0.f;
#pragma unroll 8
        for (int f = 0; f < FF; f += 4) {
            float4 c4 = *(const float4*)(wc + f);
            float4 b4 = *(const float4*)(wb + f);
            ac += c4.x * prc[f] + c4.y * prc[f + 1] + c4.z * prc[f + 2] + c4.w * prc[f + 3];
            ab += b4.x * prb[f] + b4.y * prb[f + 1] + b4.z * prb[f + 2] + b4.w * prb[f + 3];
        }
        uc[tid] = prelu_f(ac + bc1[tid], ac2p[0]);
        ub[tid] = prelu_f(ab + bb1[tid], ab2p[0]);
    }
    __syncthreads();
    if (tid < NCLS) {
        const float* w = Wc2 + tid * KH;
        float acc = bc2[tid];
#pragma unroll
        for (int q = 0; q < KH; q += 4) {
            float4 w4 = *(const float4*)(w + q);
            acc += w4.x * uc[q] + w4.y * uc[q + 1] + w4.z * uc[q + 2] + w4.w * uc[q + 3];
        }
        cls_out[(b * SS + ts) * NCLS + tid] = acc;
    }
    if (tid >= 64 && tid < 66) {
        int o = tid - 64;
        const float* w = Wb2 + o * KH;
        float acc = bb2[o];
#pragma unroll
        for (int q = 0; q < KH; q += 4) {
            float4 w4 = *(const float4*)(w + q);
            acc += w4.x * ub[q] + w4.y * ub[q + 1] + w4.z * ub[q + 2] + w4.w * ub[q + 3];
        }
        bin_out[(b * SS + ts) * 2 + o] = acc;
    }
}

// ---------------- K7: DP segment search (single wave, no barriers) ---------
__global__ void k_dp(const float* __restrict__ scoresT, const int* __restrict__ lengths,
                     float* __restrict__ predF, float* __restrict__ prevF) {
    int b = blockIdx.x;
    int lane = threadIdx.x;          // 64 threads = 1 wave: lockstep, no __syncthreads
    __shared__ float bl[BB][NN];
    for (int idx = lane; idx < NN; idx += 64) bl[b][idx] = 0.f;
    if (lane == 0) prevF[b * NN] = 0.f;

    int lo = 0, cnt = 1;
    // coalesced: scoresT[b][i][k]
    float sc = (lane < cnt) ? scoresT[(b * NN + 1) * NN + lo + lane] : 0.f;

    for (int i = 1; i <= NN - 1; ++i) {
        int myk = lo + lane;
        float cand = (lane < cnt) ? bl[b][myk] + sc : -INFINITY;
        int idx = myk;
        int lo2 = (i + 1 > MAXSEG) ? (i + 1 - MAXSEG) : 0;
        int cnt2 = i + 1 - lo2;
        float scn = 0.f;
        if (i + 1 <= NN - 1 && lane < cnt2)
            scn = scoresT[(b * NN + (i + 1)) * NN + lo2 + lane];
#pragma unroll
        for (int off = 32; off; off >>= 1) {
            float vo = __shfl_down(cand, off);
            int io = __shfl_down(idx, off);
            if (vo > cand || (vo == cand && io < idx)) { cand = vo; idx = io; }
        }
        if (lane == 0) {
            bl[b][i] = cand;
            prevF[b * NN + i] = (float)idx;
        }
        __builtin_amdgcn_wave_barrier();   // compiler fence only (no HW cost)
        sc = scn;
        lo = lo2; cnt = cnt2;
    }
    if (lane == 0) {
        int len = lengths[b];
        predF[b] = bl[b][len];
    }
}

// ---------------- launch ---------------------------------------------------
extern "C" void kernel_launch(void* const* d_in, const int* in_sizes, int n_in,
                              void* d_out, int out_size, void* d_ws, size_t ws_size,
                              hipStream_t stream) {
    const float* x    = (const float*)d_in[0];
    const int* lengths= (const int*)d_in[1];
    const float* Wi_f = (const float*)d_in[2];
    const float* Wh_f = (const float*)d_in[3];
    const float* b_f  = (const float*)d_in[4];
    const float* Wi_b = (const float*)d_in[5];
    const float* Wh_b = (const float*)d_in[6];
    const float* b_b  = (const float*)d_in[7];
    const float* a1   = (const float*)d_in[8];
    const float* W1   = (const float*)d_in[9];
    const float* b1   = (const float*)d_in[10];
    const float* a2   = (const float*)d_in[11];
    const float* W2   = (const float*)d_in[12];
    const float* b2   = (const float*)d_in[13];
    const float* ac1  = (const float*)d_in[14];
    const float* Wc1  = (const float*)d_in[15];
    const float* bc1  = (const float*)d_in[16];
    const float* ac2  = (const float*)d_in[17];
    const float* Wc2  = (const float*)d_in[18];
    const float* bc2  = (const float*)d_in[19];
    const float* ab1  = (const float*)d_in[20];
    const float* Wb1  = (const float*)d_in[21];
    const float* bb1  = (const float*)d_in[22];
    const float* ab2  = (const float*)d_in[23];
    const float* Wb2  = (const float*)d_in[24];
    const float* bb2  = (const float*)d_in[25];

    float* out = (float*)d_out;
    float* scores = out + SCORES_OFF;
    float* cls    = out + CLS_OFF;
    float* bin    = out + BIN_OFF;
    float* pred   = out + PRED_OFF;
    float* prev   = out + PREV_OFF;

    float* ws   = (float*)d_ws;
    float* gx   = ws + WS_GX;
    float* scoresT = ws + WS_GX;     // reuse: gx dead after k_lstm_rec
    float* rnn  = ws + WS_RNN;
    float* cum  = ws + WS_CUM;
    float* pxd  = ws + WS_PXD;
    float* pxe  = ws + WS_PXE;
    float* part = ws + WS_PART;
    short* wH   = (short*)(ws + WS_WH);
    short* wL   = (short*)(ws + WS_WL);
    float* w2p  = ws + WS_W2P;
    float* b1p  = ws + WS_B1P;

    k_prep<<<KP, FF, 0, stream>>>(W1, W2, b1, wH, wL, w2p, b1p);
    k_lstm_pre<<<4 * SS, 256, 0, stream>>>(x, Wi_f, b_f, Wi_b, b_b, gx);
    k_lstm_rec<<<4, 512, 0, stream>>>(Wh_f, Wh_b, gx, rnn);
    k_cum_part<<<BB * NCH, FF, 0, stream>>>(rnn, part);
    k_cum_off<<<BB, FF, 0, stream>>>(part);
    k_cum_write<<<BB * NCH, FF, 0, stream>>>(rnn, part, cum);
    k_pxde<<<BB * NN, 256, 0, stream>>>(rnn, W1, a1, pxd, pxe);
    k_scores<<<BB * NN * JTILES, 256, 0, stream>>>(cum, wH, wL, pxd, pxe, b1p, w2p, b2,
                                                   a1, a2, scores, scoresT);
    k_heads<<<BB * SS, 128, 0, stream>>>(rnn, ac1, Wc1, bc1, ac2, Wc2, bc2,
                                         ab1, Wb1, bb1, ab2, Wb2, bb2, cls, bin);
    k_dp<<<BB, 64, 0, stream>>>(scoresT, lengths, pred, prev);
}

// Round 5
// 1019.015 us; speedup vs baseline: 1.9585x; 1.0116x over previous
//
#include <hip/hip_runtime.h>
#include <math.h>

// Problem constants
#define BB 2
#define SS 400
#define II 80
#define HH 128
#define FF 256          // 2*H
#define NN 401          // S+1
#define G4 512          // 4*H
#define MAXSEG 50
#define NCLS 50
#define KH 100          // rows of W1 / Wc1 / Wb1
#define KP 112          // KH padded to 7*16 for MFMA

// d_out layout (floats): scores | cls | bin | pred | prev
#define SCORES_OFF 0
#define CLS_OFF    (BB*NN*NN)
#define BIN_OFF    (CLS_OFF + BB*SS*NCLS)
#define PRED_OFF   (BIN_OFF + BB*SS*2)
#define PREV_OFF   (PRED_OFF + BB)

// workspace layout (float slots)
#define WS_GX      0                          // 4*S*512 = 819200 (dead after k_lstm_rec;
                                              // reused as scoresT: BB*NN*NN = 321602)
#define WS_RNN     (WS_GX + 4*SS*G4)          // B*S*F
#define WS_CUM     (WS_RNN + BB*SS*FF)        // B*N*F
#define WS_PXD     (WS_CUM + BB*NN*FF)        // B*N*KP
#define WS_PXE     (WS_PXD + BB*NN*KP)
#define WS_PART    (WS_PXE + BB*NN*KP)        // B*16*F
#define WS_WH      (WS_PART + BB*16*FF)       // W1c hi bf16: KP*FF shorts
#define WS_WL      (WS_WH + (KP*FF)/2)
#define WS_W2P     (WS_WL + (KP*FF)/2)        // KP floats
#define WS_B1P     (WS_W2P + KP)              // KP floats

typedef __attribute__((ext_vector_type(8))) short short8;
typedef __attribute__((ext_vector_type(4))) float f32x4;

__device__ __forceinline__ float prelu_f(float x, float a) {
    return x >= 0.f ? x : a * x;
}
__device__ __forceinline__ unsigned short f2bf(float x) {
    union { float f; unsigned u; } v; v.f = x;
    unsigned r = v.u + 0x7fffu + ((v.u >> 16) & 1u);   // RNE
    return (unsigned short)(r >> 16);
}
__device__ __forceinline__ float bf2f(unsigned short h) {
    union { unsigned u; float f; } v; v.u = ((unsigned)h) << 16; return v.f;
}
__device__ __forceinline__ float fast_sigmoid(float x) {
    return 1.f / (1.f + __expf(-x));
}
__device__ __forceinline__ float fast_tanh(float x) {
    return 1.f - 2.f / (1.f + __expf(2.f * x));
}

// ---------------- K0: prep W1c bf16 hi/lo + padded W2/b1 -------------------
__global__ void k_prep(const float* __restrict__ W1, const float* __restrict__ W2,
                       const float* __restrict__ b1,
                       short* __restrict__ wh, short* __restrict__ wl,
                       float* __restrict__ w2p, float* __restrict__ b1p) {
    int k = blockIdx.x;        // 0..111
    int f = threadIdx.x;       // 0..255
    float w = (k < KH) ? W1[k * (3 * FF) + f] : 0.f;
    unsigned short hi = f2bf(w);
    unsigned short lo = f2bf(w - bf2f(hi));
    wh[k * FF + f] = (short)hi;
    wl[k * FF + f] = (short)lo;
    if (f == 0) {
        w2p[k] = (k < KH) ? W2[k] : 0.f;
        b1p[k] = (k < KH) ? b1[k] : 0.f;
    }
}

// ---------------- K1: gx[db][t][g] = b[g] + x[b, xt, :] . Wi[g, :] ---------
__global__ void k_lstm_pre(const float* __restrict__ x,
                           const float* __restrict__ Wi_f, const float* __restrict__ b_f,
                           const float* __restrict__ Wi_b, const float* __restrict__ b_b,
                           float* __restrict__ gx) {
    int blk = blockIdx.x;          // db*S + t
    int t = blk % SS;
    int db = blk / SS;             // dir*2 + b
    int b = db & 1, dir = db >> 1;
    const float* Wi = dir ? Wi_b : Wi_f;
    const float* bias = dir ? b_b : b_f;
    int xt = dir ? (SS - 1 - t) : t;

    __shared__ __align__(16) float xr[II];
    int tid = threadIdx.x;
    if (tid < II) xr[tid] = x[(b * SS + xt) * II + tid];
    __syncthreads();

    for (int g = tid; g < G4; g += 256) {
        const float* w = Wi + g * II;
        float acc = bias[g];
#pragma unroll
        for (int i = 0; i < II; i += 4) {
            float4 w4 = *(const float4*)(w + i);
            acc += w4.x * xr[i] + w4.y * xr[i + 1] + w4.z * xr[i + 2] + w4.w * xr[i + 3];
        }
        gx[(db * SS + t) * G4 + g] = acc;
    }
}

// ---------------- K2: recurrent LSTM, 4 blocks (dir,b), 512 threads --------
// Same structure as R4 (8-gate octets, k-slice 16, butterfly reduce, one
// barrier/step). KEY CHANGE: __launch_bounds__(512, 1) -> up to 256 VGPRs so
// the 128-float weight array stays in arch VGPRs (R4's (512,2) bound forced
// AGPR parking: VGPR_Count=84 with v_accvgpr_read per FMA ~2x inst stream).
__global__ __launch_bounds__(512, 1)
void k_lstm_rec(const float* __restrict__ Wh_f, const float* __restrict__ Wh_b,
                const float* __restrict__ gx, float* __restrict__ rnn_out) {
    int db = blockIdx.x;
    int b = db & 1, dir = db >> 1;
    const float* Wh = dir ? Wh_b : Wh_f;
    int tid = threadIdx.x;
    int w = tid >> 6;
    int l = tid & 63;
    int q = l >> 3;
    int s = l & 7;
    int u0 = (w * 8 + q) * 2;
    int kbase = s * 16;

    // weights: 8 gates (gl = (usel<<2)|type) x 16 k -> 128 VGPRs
    float4 wv[8][4];
#pragma unroll
    for (int gl = 0; gl < 8; ++gl) {
        int gid = (gl & 3) * 128 + u0 + (gl >> 2);
        const float* wr = Wh + gid * HH + kbase;
#pragma unroll
        for (int c = 0; c < 4; ++c) wv[gl][c] = *(const float4*)(wr + c * 4);
    }

    int mygid = (s & 3) * 128 + u0 + (s >> 2);   // gate this lane ends up holding
    int myunit = u0 + (s >> 2);
    bool is_lead = (s & 3) == 0;

    __shared__ __align__(16) float hsp[2][8 * 20];   // 2 buffers, padded slices
    for (int i = tid; i < 2 * 160; i += 512) (&hsp[0][0])[i] = 0.f;
    float c_state = 0.f;
    __syncthreads();

    const float* gxp = gx + db * SS * G4;
    float gcur = gxp[mygid];                   // prefetch step 0
    int pb = 0;
    for (int step = 0; step < SS; ++step) {
        float gnext = (step + 1 < SS) ? gxp[(step + 1) * G4 + mygid] : 0.f;
        float4 h0 = *(const float4*)(&hsp[pb][s * 20]);
        float4 h1 = *(const float4*)(&hsp[pb][s * 20 + 4]);
        float4 h2 = *(const float4*)(&hsp[pb][s * 20 + 8]);
        float4 h3 = *(const float4*)(&hsp[pb][s * 20 + 12]);
        float v[8];
#pragma unroll
        for (int gl = 0; gl < 8; ++gl) {
            float4 wa = wv[gl][0], wb = wv[gl][1], wc = wv[gl][2], wd = wv[gl][3];
            float p0 = wa.x * h0.x + wa.y * h0.y + wa.z * h0.z + wa.w * h0.w;
            float p1 = wb.x * h1.x + wb.y * h1.y + wb.z * h1.z + wb.w * h1.w;
            float p2 = wc.x * h2.x + wc.y * h2.y + wc.z * h2.z + wc.w * h2.w;
            float p3 = wd.x * h3.x + wd.y * h3.y + wd.z * h3.z + wd.w * h3.w;
            v[gl] = (p0 + p1) + (p2 + p3);
        }
        // butterfly over s: lane s ends with full sum for gl = s
        float u4[4];
#pragma unroll
        for (int j = 0; j < 4; ++j) {
            float snd = (s & 4) ? v[j] : v[j + 4];
            float kp  = (s & 4) ? v[j + 4] : v[j];
            u4[j] = kp + __shfl_xor(snd, 4);
        }
        float u2[2];
#pragma unroll
        for (int j = 0; j < 2; ++j) {
            float snd = (s & 2) ? u4[j] : u4[j + 2];
            float kp  = (s & 2) ? u4[j + 2] : u4[j];
            u2[j] = kp + __shfl_xor(snd, 2);
        }
        {
            float snd = (s & 1) ? u2[0] : u2[1];
            float kp  = (s & 1) ? u2[1] : u2[0];
            float gate = kp + __shfl_xor(snd, 1) + gcur;
            // activation: type = s&3 (0=i,1=f,2=g,3=o)
            float act = ((s & 3) == 2) ? fast_tanh(gate) : fast_sigmoid(gate);
            float r1 = __shfl_xor(act, 1);   // lead: sigma(f)
            float p0 = __shfl_xor(act, 2);   // lead: tanh(g)
            float p1 = __shfl_xor(r1, 2);    // lead: sigma(o)
            if (is_lead) {
                c_state = r1 * c_state + act * p0;
                float h = p1 * fast_tanh(c_state);
                hsp[pb ^ 1][(myunit >> 4) * 20 + (myunit & 15)] = h;
                int xt = dir ? (SS - 1 - step) : step;
                rnn_out[(b * SS + xt) * FF + dir * HH + myunit] = h;
            }
        }
        __syncthreads();
        pb ^= 1;
        gcur = gnext;
    }
}

// ---------------- K3: cumsum over time (3 passes) --------------------------
#define CHUNK 25
#define NCH 16
__global__ void k_cum_part(const float* __restrict__ rnn, float* __restrict__ part) {
    int blk = blockIdx.x;           // b*NCH + c
    int c = blk % NCH, b = blk / NCH;
    int f = threadIdx.x;
    float s = 0.f;
    for (int r = 0; r < CHUNK; ++r) s += rnn[(b * SS + c * CHUNK + r) * FF + f];
    part[blk * FF + f] = s;
}
__global__ void k_cum_off(float* __restrict__ part) {
    int b = blockIdx.x;
    int f = threadIdx.x;
    float run = 0.f;
    for (int c = 0; c < NCH; ++c) {
        int idx = (b * NCH + c) * FF + f;
        float tmp = part[idx];
        part[idx] = run;
        run += tmp;
    }
}
__global__ void k_cum_write(const float* __restrict__ rnn, const float* __restrict__ part,
                            float* __restrict__ cum) {
    int blk = blockIdx.x;           // b*NCH + c
    int c = blk % NCH, b = blk / NCH;
    int f = threadIdx.x;
    float run = part[blk * FF + f];
    cum[(b * NN + c * CHUNK) * FF + f] = run;
    for (int idx = 1; idx <= CHUNK; ++idx) {
        run += rnn[(b * SS + c * CHUNK + idx - 1) * FF + f];
        cum[(b * NN + c * CHUNK + idx) * FF + f] = run;
    }
}

// ---------------- K4: fused pxd/pxe (blk<802) + cls/bin heads (blk>=802) ---
__global__ void k_pxde_heads(const float* __restrict__ rnn, const float* __restrict__ W1,
                             const float* __restrict__ a1p,
                             float* __restrict__ pxd, float* __restrict__ pxe,
                             const float* __restrict__ ac1p, const float* __restrict__ Wc1,
                             const float* __restrict__ bc1, const float* __restrict__ ac2p,
                             const float* __restrict__ Wc2, const float* __restrict__ bc2,
                             const float* __restrict__ ab1p, const float* __restrict__ Wb1,
                             const float* __restrict__ bb1, const float* __restrict__ ab2p,
                             const float* __restrict__ Wb2, const float* __restrict__ bb2,
                             float* __restrict__ cls_out, float* __restrict__ bin_out) {
    int blk = blockIdx.x;
    int tid = threadIdx.x;
    if (blk < BB * NN) {
        // ---- pxde path ----
        int n = blk % NN, b = blk / NN;
        float a1 = a1p[0];
        __shared__ __align__(16) float px[FF];
        float rv = (n == 0) ? 0.f : rnn[(b * SS + n - 1) * FF + tid];
        px[tid] = prelu_f(rv, a1);
        __syncthreads();

        if (tid < KH) {
            const float* w = W1 + tid * (3 * FF) + FF;    // W1d row
            float acc = 0.f;
#pragma unroll 8
            for (int f = 0; f < FF; f += 4) {
                float4 w4 = *(const float4*)(w + f);
                acc += w4.x * px[f] + w4.y * px[f + 1] + w4.z * px[f + 2] + w4.w * px[f + 3];
            }
            pxd[blk * KP + tid] = acc;
        } else if (tid >= KH && tid < KP) {
            pxd[blk * KP + tid] = 0.f;                    // pad
        } else if (tid >= 128 && tid < 128 + KH) {
            int k = tid - 128;
            const float* w = W1 + k * (3 * FF) + 2 * FF;  // W1e row
            float acc = 0.f;
#pragma unroll 8
            for (int f = 0; f < FF; f += 4) {
                float4 w4 = *(const float4*)(w + f);
                acc += w4.x * px[f] + w4.y * px[f + 1] + w4.z * px[f + 2] + w4.w * px[f + 3];
            }
            pxe[blk * KP + k] = acc;
        } else if (tid >= 128 + KH && tid < 128 + KP) {
            pxe[blk * KP + (tid - 128)] = 0.f;            // pad
        }
    } else {
        // ---- heads path ----
        int hb = blk - BB * NN;         // b*S + t
        int ts = hb % SS, b = hb / SS;
        __shared__ __align__(16) float prc[FF], prb[FF];
        __shared__ __align__(16) float uc[KH], ub[KH];
        float ac1 = ac1p[0], ab1 = ab1p[0];
        float rv = rnn[(b * SS + ts) * FF + tid];
        prc[tid] = prelu_f(rv, ac1);
        prb[tid] = prelu_f(rv, ab1);
        __syncthreads();
        if (tid < KH) {
            const float* wc = Wc1 + tid * FF;
            float ac = 0.f;
#pragma unroll 8
            for (int f = 0; f < FF; f += 4) {
                float4 c4 = *(const float4*)(wc + f);
                ac += c4.x * prc[f] + c4.y * prc[f + 1] + c4.z * prc[f + 2] + c4.w * prc[f + 3];
            }
            uc[tid] = prelu_f(ac + bc1[tid], ac2p[0]);
        } else if (tid >= 128 && tid < 128 + KH) {
            int k = tid - 128;
            const float* wb = Wb1 + k * FF;
            float ab = 0.f;
#pragma unroll 8
            for (int f = 0; f < FF; f += 4) {
                float4 b4 = *(const float4*)(wb + f);
                ab += b4.x * prb[f] + b4.y * prb[f + 1] + b4.z * prb[f + 2] + b4.w * prb[f + 3];
            }
            ub[k] = prelu_f(ab + bb1[k], ab2p[0]);
        }
        __syncthreads();
        if (tid < NCLS) {
            const float* w = Wc2 + tid * KH;
            float acc = bc2[tid];
#pragma unroll
            for (int q = 0; q < KH; q += 4) {
                float4 w4 = *(const float4*)(w + q);
                acc += w4.x * uc[q] + w4.y * uc[q + 1] + w4.z * uc[q + 2] + w4.w * uc[q + 3];
            }
            cls_out[(b * SS + ts) * NCLS + tid] = acc;
        }
        if (tid >= 64 && tid < 66) {
            int o = tid - 64;
            const float* w = Wb2 + o * KH;
            float acc = bb2[o];
#pragma unroll
            for (int q = 0; q < KH; q += 4) {
                float4 w4 = *(const float4*)(w + q);
                acc += w4.x * ub[q] + w4.y * ub[q + 1] + w4.z * ub[q + 2] + w4.w * ub[q + 3];
            }
            bin_out[(b * SS + ts) * 2 + o] = acc;
        }
    }
}

// ---------------- K5: scores via MFMA (bf16 hi/lo split A, bf16 W) ---------
#define JT 32
#define JTILES 13
#define AP 264          // row stride in shorts (256 + 8 pad)
__global__ __launch_bounds__(256, 2)
void k_scores(const float* __restrict__ cum,
              const short* __restrict__ wh, const short* __restrict__ wl,
              const float* __restrict__ pxd, const float* __restrict__ pxe,
              const float* __restrict__ b1p, const float* __restrict__ w2p,
              const float* __restrict__ b2p,
              const float* __restrict__ a1p, const float* __restrict__ a2p,
              float* __restrict__ scores, float* __restrict__ scoresT) {
    int blk = blockIdx.x;
    int jt = blk % JTILES;
    int i = (blk / JTILES) % NN;
    int b = blk / (JTILES * NN);
    int tid = threadIdx.x;
    float a1 = a1p[0], a2 = a2p[0];
    int jbase = jt * JT;

    __shared__ __align__(16) float ci[FF];
    __shared__ __align__(16) short dth[JT][AP];
    __shared__ __align__(16) short dtl[JT][AP];
    __shared__ float red[4][JT];

    ci[tid] = cum[(b * NN + i) * FF + tid];
    __syncthreads();

    {
        int row = tid >> 3;
        int fb = (tid & 7) * 32;
        int jg = jbase + row;
        int jc = (jg <= SS) ? jg : SS;
        const float* cj = cum + (b * NN + jc) * FF + fb;
#pragma unroll
        for (int c8 = 0; c8 < 4; ++c8) {
            float4 v0 = *(const float4*)(cj + c8 * 8);
            float4 v1 = *(const float4*)(cj + c8 * 8 + 4);
            union { short8 s; unsigned short u[8]; } h8, l8;
            float dv[8] = { v0.x, v0.y, v0.z, v0.w, v1.x, v1.y, v1.z, v1.w };
#pragma unroll
            for (int e = 0; e < 8; ++e) {
                float d = prelu_f(dv[e] - ci[fb + c8 * 8 + e], a1);
                unsigned short hi = f2bf(d);
                h8.u[e] = hi;
                l8.u[e] = f2bf(d - bf2f(hi));
            }
            *(short8*)(&dth[row][fb + c8 * 8]) = h8.s;
            *(short8*)(&dtl[row][fb + c8 * 8]) = l8.s;
        }
    }
    __syncthreads();

    int lane = tid & 63;
    int wv = tid >> 6;
    int quad = lane >> 4;
    int l15 = lane & 15;
    int kt0 = wv * 2, kt1 = wv * 2 + 1;
    bool has1 = (kt1 < 7);

    short8 bh0[8], bl0[8], bh1[8], bl1[8];
    {
        const short8* ph0 = (const short8*)(wh + (kt0 * 16 + l15) * FF);
        const short8* pl0 = (const short8*)(wl + (kt0 * 16 + l15) * FF);
        int k1row = has1 ? (kt1 * 16 + l15) : 0;
        const short8* ph1 = (const short8*)(wh + k1row * FF);
        const short8* pl1 = (const short8*)(wl + k1row * FF);
#pragma unroll
        for (int ks = 0; ks < 8; ++ks) {
            bh0[ks] = ph0[ks * 4 + quad];
            bl0[ks] = pl0[ks * 4 + quad];
            bh1[ks] = ph1[ks * 4 + quad];
            bl1[ks] = pl1[ks * 4 + quad];
        }
    }

    int kout0 = kt0 * 16 + l15;
    int kout1 = has1 ? (kt1 * 16 + l15) : 0;
    float pd0 = pxd[(b * NN + i) * KP + kout0];
    float pd1 = pxd[(b * NN + i) * KP + kout1];
    float bb0 = b1p[kout0], bb1v = b1p[kout1];
    float w20 = w2p[kout0];
    float w21 = has1 ? w2p[kout1] : 0.f;

#pragma unroll
    for (int mt = 0; mt < 2; ++mt) {
        short8 ah[8], al[8];
        {
            int arow = mt * 16 + l15;
            const short* base_h = &dth[0][0] + arow * AP;
            const short* base_l = &dtl[0][0] + arow * AP;
#pragma unroll
            for (int ks = 0; ks < 8; ++ks) {
                ah[ks] = *(const short8*)(base_h + ks * 32 + quad * 8);
                al[ks] = *(const short8*)(base_l + ks * 32 + quad * 8);
            }
        }
        f32x4 acc0 = {0.f, 0.f, 0.f, 0.f};
        f32x4 acc1 = {0.f, 0.f, 0.f, 0.f};
#pragma unroll
        for (int ks = 0; ks < 8; ++ks) {
            acc0 = __builtin_amdgcn_mfma_f32_16x16x32_bf16(ah[ks], bh0[ks], acc0, 0, 0, 0);
            acc0 = __builtin_amdgcn_mfma_f32_16x16x32_bf16(al[ks], bl0[ks], acc0, 0, 0, 0);
            if (has1) {
                acc1 = __builtin_amdgcn_mfma_f32_16x16x32_bf16(ah[ks], bh1[ks], acc1, 0, 0, 0);
                acc1 = __builtin_amdgcn_mfma_f32_16x16x32_bf16(al[ks], bl1[ks], acc1, 0, 0, 0);
            }
        }
#pragma unroll
        for (int r = 0; r < 4; ++r) {
            int m = mt * 16 + quad * 4 + r;
            int jg = jbase + m;
            int jc = (jg <= SS) ? jg : SS;
            float pe0 = pxe[(b * NN + jc) * KP + kout0];
            float pe1 = pxe[(b * NN + jc) * KP + kout1];
            float h0 = acc0[r] + pd0 + pe0 + bb0;
            float s = w20 * prelu_f(h0, a2);
            float h1 = acc1[r] + pd1 + pe1 + bb1v;
            s += w21 * prelu_f(h1, a2);
            s += __shfl_xor(s, 1);
            s += __shfl_xor(s, 2);
            s += __shfl_xor(s, 4);
            s += __shfl_xor(s, 8);
            if (l15 == 0) red[wv][m] = s;
        }
    }
    __syncthreads();
    if (tid < JT) {
        int jg = jbase + tid;
        if (jg <= SS) {
            float tot = red[0][tid] + red[1][tid] + red[2][tid] + red[3][tid] + b2p[0];
            scores[(b * NN + i) * NN + jg] = tot;
            scoresT[(b * NN + jg) * NN + i] = tot;   // transposed copy for k_dp
        }
    }
}

// ---------------- K7: DP segment search (single wave, no barriers) ---------
__global__ void k_dp(const float* __restrict__ scoresT, const int* __restrict__ lengths,
                     float* __restrict__ predF, float* __restrict__ prevF) {
    int b = blockIdx.x;
    int lane = threadIdx.x;          // 64 threads = 1 wave: lockstep, no __syncthreads
    __shared__ float bl[BB][NN];
    for (int idx = lane; idx < NN; idx += 64) bl[b][idx] = 0.f;
    if (lane == 0) prevF[b * NN] = 0.f;

    int lo = 0, cnt = 1;
    // coalesced: scoresT[b][i][k]
    float sc = (lane < cnt) ? scoresT[(b * NN + 1) * NN + lo + lane] : 0.f;

    for (int i = 1; i <= NN - 1; ++i) {
        int myk = lo + lane;
        float cand = (lane < cnt) ? bl[b][myk] + sc : -INFINITY;
        int idx = myk;
        int lo2 = (i + 1 > MAXSEG) ? (i + 1 - MAXSEG) : 0;
        int cnt2 = i + 1 - lo2;
        float scn = 0.f;
        if (i + 1 <= NN - 1 && lane < cnt2)
            scn = scoresT[(b * NN + (i + 1)) * NN + lo2 + lane];
#pragma unroll
        for (int off = 32; off; off >>= 1) {
            float vo = __shfl_down(cand, off);
            int io = __shfl_down(idx, off);
            if (vo > cand || (vo == cand && io < idx)) { cand = vo; idx = io; }
        }
        if (lane == 0) {
            bl[b][i] = cand;
            prevF[b * NN + i] = (float)idx;
        }
        __builtin_amdgcn_wave_barrier();   // compiler fence only (no HW cost)
        sc = scn;
        lo = lo2; cnt = cnt2;
    }
    if (lane == 0) {
        int len = lengths[b];
        predF[b] = bl[b][len];
    }
}

// ---------------- launch ---------------------------------------------------
extern "C" void kernel_launch(void* const* d_in, const int* in_sizes, int n_in,
                              void* d_out, int out_size, void* d_ws, size_t ws_size,
                              hipStream_t stream) {
    const float* x    = (const float*)d_in[0];
    const int* lengths= (const int*)d_in[1];
    const float* Wi_f = (const float*)d_in[2];
    const float* Wh_f = (const float*)d_in[3];
    const float* b_f  = (const float*)d_in[4];
    const float* Wi_b = (const float*)d_in[5];
    const float* Wh_b = (const float*)d_in[6];
    const float* b_b  = (const float*)d_in[7];
    const float* a1   = (const float*)d_in[8];
    const float* W1   = (const float*)d_in[9];
    const float* b1   = (const float*)d_in[10];
    const float* a2   = (const float*)d_in[11];
    const float* W2   = (const float*)d_in[12];
    const float* b2   = (const float*)d_in[13];
    const float* ac1  = (const float*)d_in[14];
    const float* Wc1  = (const float*)d_in[15];
    const float* bc1  = (const float*)d_in[16];
    const float* ac2  = (const float*)d_in[17];
    const float* Wc2  = (const float*)d_in[18];
    const float* bc2  = (const float*)d_in[19];
    const float* ab1  = (const float*)d_in[20];
    const float* Wb1  = (const float*)d_in[21];
    const float* bb1  = (const float*)d_in[22];
    const float* ab2  = (const float*)d_in[23];
    const float* Wb2  = (const float*)d_in[24];
    const float* bb2  = (const float*)d_in[25];

    float* out = (float*)d_out;
    float* scores = out + SCORES_OFF;
    float* cls    = out + CLS_OFF;
    float* bin    = out + BIN_OFF;
    float* pred   = out + PRED_OFF;
    float* prev   = out + PREV_OFF;

    float* ws   = (float*)d_ws;
    float* gx   = ws + WS_GX;
    float* scoresT = ws + WS_GX;     // reuse: gx dead after k_lstm_rec
    float* rnn  = ws + WS_RNN;
    float* cum  = ws + WS_CUM;
    float* pxd  = ws + WS_PXD;
    float* pxe  = ws + WS_PXE;
    float* part = ws + WS_PART;
    short* wH   = (short*)(ws + WS_WH);
    short* wL   = (short*)(ws + WS_WL);
    float* w2p  = ws + WS_W2P;
    float* b1p  = ws + WS_B1P;

    k_prep<<<KP, FF, 0, stream>>>(W1, W2, b1, wH, wL, w2p, b1p);
    k_lstm_pre<<<4 * SS, 256, 0, stream>>>(x, Wi_f, b_f, Wi_b, b_b, gx);
    k_lstm_rec<<<4, 512, 0, stream>>>(Wh_f, Wh_b, gx, rnn);
    k_cum_part<<<BB * NCH, FF, 0, stream>>>(rnn, part);
    k_cum_off<<<BB, FF, 0, stream>>>(part);
    k_cum_write<<<BB * NCH, FF, 0, stream>>>(rnn, part, cum);
    k_pxde_heads<<<BB * NN + BB * SS, 256, 0, stream>>>(rnn, W1, a1, pxd, pxe,
                                                        ac1, Wc1, bc1, ac2, Wc2, bc2,
                                                        ab1, Wb1, bb1, ab2, Wb2, bb2,
                                                        cls, bin);
    k_scores<<<BB * NN * JTILES, 256, 0, stream>>>(cum, wH, wL, pxd, pxe, b1p, w2p, b2,
                                                   a1, a2, scores, scoresT);
    k_dp<<<BB, 64, 0, stream>>>(scoresT, lengths, pred, prev);
}